// Round 1
// baseline (727.996 us; speedup 1.0000x reference)
//
#include <hip/hip_runtime.h>
#include <math.h>

#define BATCH 8
#define NPTS  1024
#define KNN   20
#define BNF   0.99999500003749937f  // 1/sqrt(1+1e-5)

__device__ __forceinline__ float leakyf(float x){ return x >= 0.f ? x : 0.2f*x; }

__device__ __forceinline__ void atomicMaxFloat(float* addr, float val){
  if (val >= 0.f) atomicMax((int*)addr, __float_as_int(val));
  else            atomicMin((unsigned int*)addr, __float_as_uint(val));
}

// ---------------- init p1/p2 to -inf ----------------
__global__ void k_init(float* p1, float* p2){
  int i = blockIdx.x*256 + threadIdx.x;
  if (i < BATCH*1024){ p1[i] = -INFINITY; p2[i] = -INFINITY; }
}

// ---------------- transpose x (B,3,N) -> xt (B,N,3) ----------------
__global__ void k_transpose(const float* __restrict__ x, float* __restrict__ xt){
  int gid = blockIdx.x*256 + threadIdx.x;
  if (gid >= BATCH*3*NPTS) return;
  int b = gid / (3*NPTS); int r = gid % (3*NPTS); int c = r / NPTS; int n = r % NPTS;
  xt[b*NPTS*3 + n*3 + c] = x[gid];
}

// ---------------- pack W2/W3/W4 into UV-stacked (and folded) form ----------------
__global__ void k_pack(const float* __restrict__ W2, const float* __restrict__ W3,
                       const float* __restrict__ W4,
                       float* __restrict__ W2p, float* __restrict__ W3p, float* __restrict__ W4p){
  int gid = blockIdx.x*256 + threadIdx.x;
  if (gid < 128*64){
    int o = gid / 64, c = gid % 64;
    W2p[gid] = (o < 64) ? W2[o*128 + c] : W2[(o-64)*128 + 64 + c];
  }
  int g3 = gid - 128*64;
  if (g3 >= 0 && g3 < 512*128){
    int o = g3 / 128, c = g3 % 128;
    W3p[g3] = (o < 256) ? (W3[o*512 + c]        + W3[o*512 + 128 + c])
                        : (W3[(o-256)*512 + 256 + c] + W3[(o-256)*512 + 384 + c]);
  }
  int g4 = gid - 128*64 - 512*128;
  if (g4 >= 0 && g4 < 512*256){
    int o = g4 / 256, c = g4 % 256;
    W4p[g4] = (o < 256) ? W4[o*512 + c] : W4[(o-256)*512 + 256 + c];
  }
}

// ---------------- EC1 U/V (K=3), out (B*N,128) = [U(64)|V(64)] ----------------
__global__ void k_uv1(const float* __restrict__ xt, const float* __restrict__ W1,
                      float* __restrict__ UV){
  int p = blockIdx.x;          // b*N + n
  int o = threadIdx.x;         // 0..127
  const float* xp = xt + p*3;
  float x0 = xp[0], x1 = xp[1], x2 = xp[2];
  const float* w = (o < 64) ? (W1 + o*6) : (W1 + (o-64)*6 + 3);
  UV[(long)p*128 + o] = w[0]*x0 + w[1]*x1 + w[2]*x2;
}

// ---------------- neg pairwise sq-dist, C=3 ----------------
__global__ void k_dist3(const float* __restrict__ xt, float* __restrict__ D){
  int p = blockIdx.x; int b = p >> 10; int i = p & 1023;
  const float* base = xt + (long)b*NPTS*3;
  float x0 = base[i*3], x1 = base[i*3+1], x2 = base[i*3+2];
  float* Drow = D + (long)p*NPTS;
  for (int s = 0; s < 4; ++s){
    int j = threadIdx.x + s*256;
    float d0 = x0 - base[j*3], d1 = x1 - base[j*3+1], d2 = x2 - base[j*3+2];
    Drow[j] = -(d0*d0 + d1*d1 + d2*d2);
  }
}

// ---------------- row squared norms ----------------
__global__ void k_norms(const float* __restrict__ A, int lda, int C, float* __restrict__ nrm){
  int p = blockIdx.x*256 + threadIdx.x;
  if (p >= BATCH*NPTS) return;
  const float* a = A + (long)p*lda;
  float s = 0.f;
  for (int c = 0; c < C; c += 4){
    float4 v = *(const float4*)(a + c);
    s += v.x*v.x; s += v.y*v.y; s += v.z*v.z; s += v.w*v.w;
  }
  nrm[p] = s;
}

// ---------------- top-20 per row (max value, lowest index) ----------------
__global__ void k_topk(const float* __restrict__ D, int* __restrict__ idx){
  int w = threadIdx.x >> 6;
  int lane = threadIdx.x & 63;
  int row = blockIdx.x*4 + w;            // b*N + i
  const float* Drow = D + (long)row*NPTS;
  float v[16];
  #pragma unroll
  for (int m = 0; m < 16; ++m) v[m] = Drow[m*64 + lane];
  int* out = idx + row*KNN;
  for (int it = 0; it < KNN; ++it){
    float bv = -INFINITY; int bi = NPTS;
    #pragma unroll
    for (int m = 0; m < 16; ++m){
      if (v[m] > bv){ bv = v[m]; bi = m*64 + lane; }   // m asc -> lowest idx on ties
    }
    #pragma unroll
    for (int off = 32; off >= 1; off >>= 1){
      float ov = __shfl_xor(bv, off, 64);
      int   oi = __shfl_xor(bi, off, 64);
      if (ov > bv || (ov == bv && oi < bi)){ bv = ov; bi = oi; }
    }
    if (lane == 0) out[it] = bi;
    if ((bi & 63) == lane){
      int slot = bi >> 6;
      #pragma unroll
      for (int m = 0; m < 16; ++m) if (m == slot) v[m] = -INFINITY;
    }
  }
}

// ---------------- generic tiled f32 GEMM: OUT = A(M x K) * Bm(O x K)^T ----------------
// POST 0: store. POST 1: D = 2*acc - nrm[i] - nrm[j]. POST 2: bn+leaky+max over rows -> pool
template<int POST>
__launch_bounds__(256)
__global__ void k_gemm(const float* __restrict__ A, int lda, long sA,
                       const float* __restrict__ Bm, int ldb, long sB,
                       float* __restrict__ out, int ldo, long sO,
                       int Ktot,
                       const float* __restrict__ nrm,
                       const float* __restrict__ gam, const float* __restrict__ bet,
                       float* __restrict__ pool)
{
  int b = blockIdx.z;
  int mt = blockIdx.x * 64, ot = blockIdx.y * 64;
  const float* Ab = A + (long)b*sA;
  const float* Bb = Bm + (long)b*sB;
  __shared__ float As[16][68];
  __shared__ float Bs[16][68];
  int t = threadIdx.x;
  int lm = t & 15, lo = t >> 4;
  int m0 = lm*4, o0 = lo*4;
  int lrow = t >> 2, lq = t & 3;
  float acc[4][4] = {};
  const float* ga = Ab + (long)(mt + lrow)*lda + lq*4;
  const float* gb = Bb + (long)(ot + lrow)*ldb + lq*4;
  for (int k0 = 0; k0 < Ktot; k0 += 16){
    float4 av = *(const float4*)(ga + k0);
    float4 bv = *(const float4*)(gb + k0);
    __syncthreads();
    As[lq*4+0][lrow]=av.x; As[lq*4+1][lrow]=av.y; As[lq*4+2][lrow]=av.z; As[lq*4+3][lrow]=av.w;
    Bs[lq*4+0][lrow]=bv.x; Bs[lq*4+1][lrow]=bv.y; Bs[lq*4+2][lrow]=bv.z; Bs[lq*4+3][lrow]=bv.w;
    __syncthreads();
    #pragma unroll
    for (int k = 0; k < 16; ++k){
      float4 a4 = *(const float4*)&As[k][m0];
      float4 b4 = *(const float4*)&Bs[k][o0];
      float aa[4] = {a4.x, a4.y, a4.z, a4.w};
      float bb[4] = {b4.x, b4.y, b4.z, b4.w};
      #pragma unroll
      for (int i = 0; i < 4; ++i)
        #pragma unroll
        for (int j = 0; j < 4; ++j)
          acc[i][j] += aa[i]*bb[j];
    }
  }
  if (POST == 0){
    float* ob = out + (long)b*sO;
    #pragma unroll
    for (int i = 0; i < 4; ++i)
      #pragma unroll
      for (int j = 0; j < 4; ++j)
        ob[(long)(mt+m0+i)*ldo + ot+o0+j] = acc[i][j];
  } else if (POST == 1){
    const float* nb = nrm + b*NPTS;
    float* ob = out + (long)b*sO;
    #pragma unroll
    for (int i = 0; i < 4; ++i){
      float ni = nb[mt+m0+i];
      #pragma unroll
      for (int j = 0; j < 4; ++j)
        ob[(long)(mt+m0+i)*ldo + ot+o0+j] = 2.f*acc[i][j] - ni - nb[ot+o0+j];
    }
  } else {
    #pragma unroll
    for (int j = 0; j < 4; ++j){
      int o = ot + o0 + j;
      float s = gam[o]*BNF, sh = bet[o];
      float mv = -INFINITY;
      #pragma unroll
      for (int i = 0; i < 4; ++i){
        float y = acc[i][j]*s + sh;
        mv = fmaxf(mv, y >= 0.f ? y : 0.2f*y);
      }
      #pragma unroll
      for (int off = 8; off >= 1; off >>= 1)
        mv = fmaxf(mv, __shfl_xor(mv, off, 64));
      if (lm == 0) atomicMaxFloat(&pool[b*NPTS + o], mv);
    }
  }
}

// ---------------- gather-max: out[p,o] = max_k leaky(bn(U[j_k]-U[p]+V[p])) ----------------
__global__ void k_gather(const float* __restrict__ UV, int ldUV,
                         const int* __restrict__ idx,
                         const float* __restrict__ gam, const float* __restrict__ bet,
                         float* __restrict__ out, int ldo, int O)
{
  int p = blockIdx.x;            // b*N + n
  int b = p >> 10;
  int o = threadIdx.x;
  float u = UV[(long)p*ldUV + o];
  float v = UV[(long)p*ldUV + O + o];
  float base = v - u;
  float s = gam[o]*BNF, sh = bet[o];
  const int* ip = idx + p*KNN;
  const float* UVb = UV + (long)(b << 10)*ldUV;
  float best = -INFINITY;
  for (int k = 0; k < KNN; ++k){
    int j = ip[k];
    float y = (UVb[(long)j*ldUV + o] + base)*s + sh;
    best = fmaxf(best, y >= 0.f ? y : 0.2f*y);
  }
  out[(long)p*ldo + o] = best;
}

// ---------------- FC layers ----------------
__global__ void k_fc1(const float* __restrict__ p1, const float* __restrict__ p2,
                      const float* __restrict__ L1, const float* __restrict__ g6,
                      const float* __restrict__ b6, float* __restrict__ f1)
{
  __shared__ float fs[2048];
  int b = blockIdx.x, t = threadIdx.x;   // 512 threads
  for (int s = 0; s < 4; ++s){
    int c = t + s*512;
    fs[c] = (c < 1024) ? p1[b*1024 + c] : p2[b*1024 + c - 1024];
  }
  __syncthreads();
  const float* w = L1 + (long)t*2048;
  float acc = 0.f;
  for (int c = 0; c < 2048; c += 4){
    float4 wv = *(const float4*)(w + c);
    acc += wv.x*fs[c] + wv.y*fs[c+1] + wv.z*fs[c+2] + wv.w*fs[c+3];
  }
  f1[b*512 + t] = leakyf(acc*g6[t]*BNF + b6[t]);
}

__global__ void k_fc2(const float* __restrict__ f1, const float* __restrict__ L2,
                      const float* __restrict__ bL2, const float* __restrict__ g7,
                      const float* __restrict__ b7, float* __restrict__ f2)
{
  __shared__ float fs[512];
  int b = blockIdx.x, t = threadIdx.x;   // 256 threads
  fs[t] = f1[b*512 + t]; fs[t+256] = f1[b*512 + t + 256];
  __syncthreads();
  const float* w = L2 + (long)t*512;
  float acc = bL2[t];
  for (int c = 0; c < 512; c += 4){
    float4 wv = *(const float4*)(w + c);
    acc += wv.x*fs[c] + wv.y*fs[c+1] + wv.z*fs[c+2] + wv.w*fs[c+3];
  }
  f2[b*256 + t] = leakyf(acc*g7[t]*BNF + b7[t]);
}

__global__ void k_fc3(const float* __restrict__ f2, const float* __restrict__ L3,
                      const float* __restrict__ bL3, float* __restrict__ out)
{
  __shared__ float fs[256];
  int b = blockIdx.x, t = threadIdx.x;   // 64 threads
  for (int s = 0; s < 4; ++s) fs[t + s*64] = f2[b*256 + t + s*64];
  __syncthreads();
  if (t < 40){
    const float* w = L3 + t*256;
    float acc = bL3[t];
    for (int c = 0; c < 256; c += 4){
      float4 wv = *(const float4*)(w + c);
      acc += wv.x*fs[c] + wv.y*fs[c+1] + wv.z*fs[c+2] + wv.w*fs[c+3];
    }
    out[b*40 + t] = acc;
  }
}

extern "C" void kernel_launch(void* const* d_in, const int* in_sizes, int n_in,
                              void* d_out, int out_size, void* d_ws, size_t ws_size,
                              hipStream_t stream) {
  const float* x   = (const float*)d_in[0];
  const float* W1  = (const float*)d_in[1];
  const float* g1  = (const float*)d_in[2];
  const float* b1  = (const float*)d_in[3];
  const float* W2  = (const float*)d_in[4];
  const float* g2  = (const float*)d_in[5];
  const float* b2  = (const float*)d_in[6];
  const float* W2m = (const float*)d_in[7];
  const float* g2m = (const float*)d_in[8];
  const float* b2m = (const float*)d_in[9];
  const float* W3  = (const float*)d_in[10];
  const float* g3  = (const float*)d_in[11];
  const float* b3  = (const float*)d_in[12];
  const float* W4  = (const float*)d_in[13];
  const float* g4  = (const float*)d_in[14];
  const float* b4  = (const float*)d_in[15];
  const float* W5  = (const float*)d_in[16];
  const float* g5  = (const float*)d_in[17];
  const float* b5  = (const float*)d_in[18];
  const float* L1  = (const float*)d_in[19];
  const float* g6  = (const float*)d_in[20];
  const float* b6  = (const float*)d_in[21];
  const float* L2  = (const float*)d_in[22];
  const float* bL2 = (const float*)d_in[23];
  const float* g7  = (const float*)d_in[24];
  const float* b7  = (const float*)d_in[25];
  const float* L3  = (const float*)d_in[26];
  const float* bL3 = (const float*)d_in[27];

  float* ws = (float*)d_ws;
  size_t off = 0;
  auto alloc = [&](size_t n)->float*{ float* p = ws + off; off += (n + 255) & ~(size_t)255; return p; };
  float* xt      = alloc((size_t)BATCH*NPTS*3);
  float* nrm     = alloc((size_t)BATCH*NPTS);
  float* D       = alloc((size_t)BATCH*NPTS*NPTS);
  int*   idx     = (int*)alloc((size_t)BATCH*NPTS*KNN);
  float* feat128 = alloc((size_t)BATCH*NPTS*128);
  float* UVbuf   = alloc((size_t)BATCH*NPTS*512);
  float* cat34   = alloc((size_t)BATCH*NPTS*512);
  float* W2p     = alloc(128*64);
  float* W3p     = alloc(512*128);
  float* W4p     = alloc(512*256);
  float* p1      = alloc((size_t)BATCH*1024);
  float* p2      = alloc((size_t)BATCH*1024);
  float* f1      = alloc((size_t)BATCH*512);
  float* f2      = alloc((size_t)BATCH*256);
  if (off * sizeof(float) > ws_size) return;  // insufficient workspace -> fail loudly

  const long sF = (long)NPTS*128;   // feat128 batch stride
  const long sC = (long)NPTS*512;   // cat34/UVbuf batch stride
  const long sD = (long)NPTS*NPTS;

  k_init<<<32, 256, 0, stream>>>(p1, p2);
  k_pack<<<800, 256, 0, stream>>>(W2, W3, W4, W2p, W3p, W4p);
  k_transpose<<<96, 256, 0, stream>>>(x, xt);

  // ---- EdgeConv 1 (C=3 -> 64) ----
  k_uv1<<<BATCH*NPTS, 128, 0, stream>>>(xt, W1, UVbuf);
  k_dist3<<<BATCH*NPTS, 256, 0, stream>>>(xt, D);
  k_topk<<<BATCH*NPTS/4, 256, 0, stream>>>(D, idx);
  k_gather<<<BATCH*NPTS, 64, 0, stream>>>(UVbuf, 128, idx, g1, b1, feat128, 128, 64);

  dim3 gD(16, 16, BATCH);
  // ---- EdgeConv 2 (C=64 -> 64) ----
  k_norms<<<32, 256, 0, stream>>>(feat128, 128, 64, nrm);
  k_gemm<1><<<gD, 256, 0, stream>>>(feat128, 128, sF, feat128, 128, sF, D, NPTS, sD, 64, nrm, nullptr, nullptr, nullptr);
  k_topk<<<BATCH*NPTS/4, 256, 0, stream>>>(D, idx);
  dim3 gUV2(16, 2, BATCH);
  k_gemm<0><<<gUV2, 256, 0, stream>>>(feat128, 128, sF, W2p, 64, 0, UVbuf, 128, sF, 64, nullptr, nullptr, nullptr, nullptr);
  k_gather<<<BATCH*NPTS, 64, 0, stream>>>(UVbuf, 128, idx, g2, b2, feat128 + 64, 128, 64);

  // ---- EdgeConv 3 (nf1=[f128,f128], folded: C=128 -> 256) ----
  k_norms<<<32, 256, 0, stream>>>(feat128, 128, 128, nrm);
  k_gemm<1><<<gD, 256, 0, stream>>>(feat128, 128, sF, feat128, 128, sF, D, NPTS, sD, 128, nrm, nullptr, nullptr, nullptr);
  k_topk<<<BATCH*NPTS/4, 256, 0, stream>>>(D, idx);
  dim3 gUV3(16, 8, BATCH);
  k_gemm<0><<<gUV3, 256, 0, stream>>>(feat128, 128, sF, W3p, 128, 0, UVbuf, 512, sC, 128, nullptr, nullptr, nullptr, nullptr);
  k_gather<<<BATCH*NPTS, 256, 0, stream>>>(UVbuf, 512, idx, g3, b3, cat34, 512, 256);

  // ---- EdgeConv 4 (C=256 -> 256) ----
  k_norms<<<32, 256, 0, stream>>>(cat34, 512, 256, nrm);
  k_gemm<1><<<gD, 256, 0, stream>>>(cat34, 512, sC, cat34, 512, sC, D, NPTS, sD, 256, nrm, nullptr, nullptr, nullptr);
  k_topk<<<BATCH*NPTS/4, 256, 0, stream>>>(D, idx);
  k_gemm<0><<<gUV3, 256, 0, stream>>>(cat34, 512, sC, W4p, 256, 0, UVbuf, 512, sC, 256, nullptr, nullptr, nullptr, nullptr);
  k_gather<<<BATCH*NPTS, 256, 0, stream>>>(UVbuf, 512, idx, g4, b4, cat34 + 256, 512, 256);

  // ---- fused pool projections (never materialize x_t1/x_t2) ----
  dim3 gP(16, 16, BATCH);
  k_gemm<2><<<gP, 256, 0, stream>>>(feat128, 128, sF, W2m, 128, 0, nullptr, 0, 0, 128, nullptr, g2m, b2m, p1);
  k_gemm<2><<<gP, 256, 0, stream>>>(cat34, 512, sC, W5, 512, 0, nullptr, 0, 0, 512, nullptr, g5, b5, p2);

  // ---- FC head ----
  k_fc1<<<BATCH, 512, 0, stream>>>(p1, p2, L1, g6, b6, f1);
  k_fc2<<<BATCH, 256, 0, stream>>>(f1, L2, bL2, g7, b7, f2);
  k_fc3<<<BATCH, 64, 0, stream>>>(f2, L3, bL3, (float*)d_out);
}

// Round 2
// 550.442 us; speedup vs baseline: 1.3226x; 1.3226x over previous
//
#include <hip/hip_runtime.h>
#include <math.h>

#define BATCH 8
#define NPTS  1024
#define KNN   20
#define BNF   0.99999500003749937f  // 1/sqrt(1+1e-5)

typedef short bf16x8 __attribute__((ext_vector_type(8)));
typedef float f32x4  __attribute__((ext_vector_type(4)));

__device__ __forceinline__ float leakyf(float x){ return x >= 0.f ? x : 0.2f*x; }

__device__ __forceinline__ void atomicMaxFloat(float* addr, float val){
  if (val >= 0.f) atomicMax((int*)addr, __float_as_int(val));
  else            atomicMin((unsigned int*)addr, __float_as_uint(val));
}

__device__ __forceinline__ unsigned short f2bf(float x){
  unsigned u = __float_as_uint(x);
  unsigned r = (u + 0x7FFFu + ((u >> 16) & 1u)) >> 16;   // RNE (no NaN/inf in data)
  return (unsigned short)r;
}
__device__ __forceinline__ float bf2f(unsigned short h){
  return __uint_as_float(((unsigned)h) << 16);
}

// ---------------- init p1/p2 to -inf ----------------
__global__ void k_init(float* p1, float* p2){
  int i = blockIdx.x*256 + threadIdx.x;
  if (i < BATCH*1024){ p1[i] = -INFINITY; p2[i] = -INFINITY; }
}

// ---------------- transpose x (B,3,N) -> xt (B,N,3) ----------------
__global__ void k_transpose(const float* __restrict__ x, float* __restrict__ xt){
  int gid = blockIdx.x*256 + threadIdx.x;
  if (gid >= BATCH*3*NPTS) return;
  int b = gid / (3*NPTS); int r = gid % (3*NPTS); int c = r / NPTS; int n = r % NPTS;
  xt[b*NPTS*3 + n*3 + c] = x[gid];
}

// ---------------- pack W2/W3/W4 into UV-stacked (and folded) form ----------------
__global__ void k_pack(const float* __restrict__ W2, const float* __restrict__ W3,
                       const float* __restrict__ W4,
                       float* __restrict__ W2p, float* __restrict__ W3p, float* __restrict__ W4p){
  int gid = blockIdx.x*256 + threadIdx.x;
  if (gid < 128*64){
    int o = gid / 64, c = gid % 64;
    W2p[gid] = (o < 64) ? W2[o*128 + c] : W2[(o-64)*128 + 64 + c];
  }
  int g3 = gid - 128*64;
  if (g3 >= 0 && g3 < 512*128){
    int o = g3 / 128, c = g3 % 128;
    W3p[g3] = (o < 256) ? (W3[o*512 + c]        + W3[o*512 + 128 + c])
                        : (W3[(o-256)*512 + 256 + c] + W3[(o-256)*512 + 384 + c]);
  }
  int g4 = gid - 128*64 - 512*128;
  if (g4 >= 0 && g4 < 512*256){
    int o = g4 / 256, c = g4 % 256;
    W4p[g4] = (o < 256) ? W4[o*512 + c] : W4[(o-256)*512 + 256 + c];
  }
}

// ---------------- split f32 -> bf16 hi/lo planes (same ld) ----------------
__global__ void k_split(const float* __restrict__ src, int ld, int cols, int total4,
                        unsigned short* __restrict__ hi, unsigned short* __restrict__ lo){
  int i = blockIdx.x*256 + threadIdx.x;
  if (i >= total4) return;
  int c4 = cols >> 2;
  int r = i / c4, c = (i % c4) * 4;
  const float* s = src + (long)r*ld + c;
  float4 v = *(const float4*)s;
  unsigned short h0 = f2bf(v.x), h1 = f2bf(v.y), h2 = f2bf(v.z), h3 = f2bf(v.w);
  unsigned short l0 = f2bf(v.x - bf2f(h0));
  unsigned short l1 = f2bf(v.y - bf2f(h1));
  unsigned short l2 = f2bf(v.z - bf2f(h2));
  unsigned short l3 = f2bf(v.w - bf2f(h3));
  *(ushort4*)(hi + (long)r*ld + c) = make_ushort4(h0, h1, h2, h3);
  *(ushort4*)(lo + (long)r*ld + c) = make_ushort4(l0, l1, l2, l3);
}

// ---------------- EC1 U/V (K=3), out (B*N,128) = [U(64)|V(64)] ----------------
__global__ void k_uv1(const float* __restrict__ xt, const float* __restrict__ W1,
                      float* __restrict__ UV){
  int p = blockIdx.x;
  int o = threadIdx.x;
  const float* xp = xt + p*3;
  float x0 = xp[0], x1 = xp[1], x2 = xp[2];
  const float* w = (o < 64) ? (W1 + o*6) : (W1 + (o-64)*6 + 3);
  UV[(long)p*128 + o] = w[0]*x0 + w[1]*x1 + w[2]*x2;
}

// ---------------- neg pairwise sq-dist, C=3 ----------------
__global__ void k_dist3(const float* __restrict__ xt, float* __restrict__ D){
  int p = blockIdx.x; int b = p >> 10; int i = p & 1023;
  const float* base = xt + (long)b*NPTS*3;
  float x0 = base[i*3], x1 = base[i*3+1], x2 = base[i*3+2];
  float* Drow = D + (long)p*NPTS;
  for (int s = 0; s < 4; ++s){
    int j = threadIdx.x + s*256;
    float d0 = x0 - base[j*3], d1 = x1 - base[j*3+1], d2 = x2 - base[j*3+2];
    Drow[j] = -(d0*d0 + d1*d1 + d2*d2);
  }
}

// ---------------- row squared norms (f32 exact) ----------------
__global__ void k_norms(const float* __restrict__ A, int lda, int C, float* __restrict__ nrm){
  int p = blockIdx.x*256 + threadIdx.x;
  if (p >= BATCH*NPTS) return;
  const float* a = A + (long)p*lda;
  float s = 0.f;
  for (int c = 0; c < C; c += 4){
    float4 v = *(const float4*)(a + c);
    s += v.x*v.x; s += v.y*v.y; s += v.z*v.z; s += v.w*v.w;
  }
  nrm[p] = s;
}

// ---------------- top-20 per row (max value, lowest index) ----------------
__global__ void k_topk(const float* __restrict__ D, int* __restrict__ idx){
  int w = threadIdx.x >> 6;
  int lane = threadIdx.x & 63;
  int row = blockIdx.x*4 + w;
  const float* Drow = D + (long)row*NPTS;
  float v[16];
  #pragma unroll
  for (int m = 0; m < 16; ++m) v[m] = Drow[m*64 + lane];
  int* out = idx + row*KNN;
  for (int it = 0; it < KNN; ++it){
    float bv = -INFINITY; int bi = NPTS;
    #pragma unroll
    for (int m = 0; m < 16; ++m){
      if (v[m] > bv){ bv = v[m]; bi = m*64 + lane; }
    }
    #pragma unroll
    for (int off = 32; off >= 1; off >>= 1){
      float ov = __shfl_xor(bv, off, 64);
      int   oi = __shfl_xor(bi, off, 64);
      if (ov > bv || (ov == bv && oi < bi)){ bv = ov; bi = oi; }
    }
    if (lane == 0) out[it] = bi;
    if ((bi & 63) == lane){
      int slot = bi >> 6;
      #pragma unroll
      for (int m = 0; m < 16; ++m) if (m == slot) v[m] = -INFINITY;
    }
  }
}

// =====================================================================
// split-bf16 MFMA GEMM: OUT(M x N) = A(M x K) * Bm(N x K)^T  (3-term hi/lo)
// block 128x128, 4 waves of 64x64, K-step 32.
// POST 0: store. POST 1: D = 2*acc - nrm[i] - nrm[j]. POST 2: bn+leaky+max_M -> pool
// =====================================================================
template<int POST>
__launch_bounds__(256)
__global__ void k_mgemm(const unsigned short* __restrict__ Ah, const unsigned short* __restrict__ Al,
                        int lda, long sA,
                        const unsigned short* __restrict__ Bh, const unsigned short* __restrict__ Bl,
                        int ldb, long sB,
                        float* __restrict__ out, int ldo, long sO, int Ktot,
                        const float* __restrict__ nrm,
                        const float* __restrict__ gam, const float* __restrict__ bet,
                        float* __restrict__ pool)
{
  __shared__ unsigned short As[2][128*32];
  __shared__ unsigned short Bs[2][128*32];
  int b = blockIdx.z;
  int mt = blockIdx.x*128, ot = blockIdx.y*128;
  const unsigned short* pA0 = Ah + (long)b*sA;
  const unsigned short* pA1 = Al + (long)b*sA;
  const unsigned short* pB0 = Bh + (long)b*sB;
  const unsigned short* pB1 = Bl + (long)b*sB;
  int t = threadIdx.x;
  int lane = t & 63, w = t >> 6;
  int wm = w >> 1, wn = w & 1;
  int frow = lane & 15, kg = lane >> 4;

  f32x4 acc[4][4] = {};

  int srow = t >> 2;          // staging row (per 256-chunk group): 0..63 then +64
  int q    = t & 3;           // 16B chunk within 64B row

  for (int k0 = 0; k0 < Ktot; k0 += 32){
    __syncthreads();
    #pragma unroll
    for (int it = 0; it < 4; ++it){
      const int plane = it >> 1;
      const int row = (it & 1)*64 + srow;
      const unsigned short* gA = (plane ? pA1 : pA0) + (long)(mt+row)*lda + k0 + q*8;
      const unsigned short* gB = (plane ? pB1 : pB0) + (long)(ot+row)*ldb + k0 + q*8;
      uint4 va = *(const uint4*)gA;
      uint4 vb = *(const uint4*)gB;
      int loff = row*32 + ((q ^ (row & 3))*8);
      *(uint4*)&As[plane][loff] = va;
      *(uint4*)&Bs[plane][loff] = vb;
    }
    __syncthreads();

    bf16x8 af[2][4], bfr[2][4];
    #pragma unroll
    for (int p = 0; p < 2; ++p){
      #pragma unroll
      for (int mi = 0; mi < 4; ++mi){
        int row = wm*64 + mi*16 + frow;
        af[p][mi] = *(const bf16x8*)&As[p][row*32 + ((kg ^ (row & 3))*8)];
      }
      #pragma unroll
      for (int ni = 0; ni < 4; ++ni){
        int row = wn*64 + ni*16 + frow;
        bfr[p][ni] = *(const bf16x8*)&Bs[p][row*32 + ((kg ^ (row & 3))*8)];
      }
    }
    #pragma unroll
    for (int mi = 0; mi < 4; ++mi){
      #pragma unroll
      for (int ni = 0; ni < 4; ++ni){
        acc[mi][ni] = __builtin_amdgcn_mfma_f32_16x16x32_bf16(af[0][mi], bfr[0][ni], acc[mi][ni], 0, 0, 0);
        acc[mi][ni] = __builtin_amdgcn_mfma_f32_16x16x32_bf16(af[0][mi], bfr[1][ni], acc[mi][ni], 0, 0, 0);
        acc[mi][ni] = __builtin_amdgcn_mfma_f32_16x16x32_bf16(af[1][mi], bfr[0][ni], acc[mi][ni], 0, 0, 0);
      }
    }
  }

  if (POST == 0){
    float* ob = out + (long)b*sO;
    #pragma unroll
    for (int mi = 0; mi < 4; ++mi){
      int grow0 = mt + wm*64 + mi*16 + kg*4;
      #pragma unroll
      for (int ni = 0; ni < 4; ++ni){
        int gcol = ot + wn*64 + ni*16 + frow;
        #pragma unroll
        for (int j = 0; j < 4; ++j)
          ob[(long)(grow0+j)*ldo + gcol] = acc[mi][ni][j];
      }
    }
  } else if (POST == 1){
    const float* nb = nrm + b*NPTS;
    float* ob = out + (long)b*sO;
    #pragma unroll
    for (int mi = 0; mi < 4; ++mi){
      int grow0 = mt + wm*64 + mi*16 + kg*4;
      #pragma unroll
      for (int ni = 0; ni < 4; ++ni){
        int gcol = ot + wn*64 + ni*16 + frow;
        float nj = nb[gcol];
        #pragma unroll
        for (int j = 0; j < 4; ++j)
          ob[(long)(grow0+j)*ldo + gcol] = 2.f*acc[mi][ni][j] - nb[grow0+j] - nj;
      }
    }
  } else {
    #pragma unroll
    for (int ni = 0; ni < 4; ++ni){
      int o = ot + wn*64 + ni*16 + frow;
      float s = gam[o]*BNF, sh = bet[o];
      float mv = -INFINITY;
      #pragma unroll
      for (int mi = 0; mi < 4; ++mi){
        #pragma unroll
        for (int j = 0; j < 4; ++j){
          float y = acc[mi][ni][j]*s + sh;
          mv = fmaxf(mv, y >= 0.f ? y : 0.2f*y);
        }
      }
      mv = fmaxf(mv, __shfl_xor(mv, 16, 64));
      mv = fmaxf(mv, __shfl_xor(mv, 32, 64));
      if (lane < 16) atomicMaxFloat(&pool[b*NPTS + o], mv);
    }
  }
}

// ---------------- legacy f32 GEMM (fallback path) ----------------
template<int POST>
__launch_bounds__(256)
__global__ void k_gemm(const float* __restrict__ A, int lda, long sA,
                       const float* __restrict__ Bm, int ldb, long sB,
                       float* __restrict__ out, int ldo, long sO,
                       int Ktot,
                       const float* __restrict__ nrm,
                       const float* __restrict__ gam, const float* __restrict__ bet,
                       float* __restrict__ pool)
{
  int b = blockIdx.z;
  int mt = blockIdx.x * 64, ot = blockIdx.y * 64;
  const float* Ab = A + (long)b*sA;
  const float* Bb = Bm + (long)b*sB;
  __shared__ float As[16][68];
  __shared__ float Bs[16][68];
  int t = threadIdx.x;
  int lm = t & 15, lo = t >> 4;
  int m0 = lm*4, o0 = lo*4;
  int lrow = t >> 2, lq = t & 3;
  float acc[4][4] = {};
  const float* ga = Ab + (long)(mt + lrow)*lda + lq*4;
  const float* gb = Bb + (long)(ot + lrow)*ldb + lq*4;
  for (int k0 = 0; k0 < Ktot; k0 += 16){
    float4 av = *(const float4*)(ga + k0);
    float4 bv = *(const float4*)(gb + k0);
    __syncthreads();
    As[lq*4+0][lrow]=av.x; As[lq*4+1][lrow]=av.y; As[lq*4+2][lrow]=av.z; As[lq*4+3][lrow]=av.w;
    Bs[lq*4+0][lrow]=bv.x; Bs[lq*4+1][lrow]=bv.y; Bs[lq*4+2][lrow]=bv.z; Bs[lq*4+3][lrow]=bv.w;
    __syncthreads();
    #pragma unroll
    for (int k = 0; k < 16; ++k){
      float4 a4 = *(const float4*)&As[k][m0];
      float4 b4 = *(const float4*)&Bs[k][o0];
      float aa[4] = {a4.x, a4.y, a4.z, a4.w};
      float bb[4] = {b4.x, b4.y, b4.z, b4.w};
      #pragma unroll
      for (int i = 0; i < 4; ++i)
        #pragma unroll
        for (int j = 0; j < 4; ++j)
          acc[i][j] += aa[i]*bb[j];
    }
  }
  if (POST == 0){
    float* ob = out + (long)b*sO;
    #pragma unroll
    for (int i = 0; i < 4; ++i)
      #pragma unroll
      for (int j = 0; j < 4; ++j)
        ob[(long)(mt+m0+i)*ldo + ot+o0+j] = acc[i][j];
  } else if (POST == 1){
    const float* nb = nrm + b*NPTS;
    float* ob = out + (long)b*sO;
    #pragma unroll
    for (int i = 0; i < 4; ++i){
      float ni = nb[mt+m0+i];
      #pragma unroll
      for (int j = 0; j < 4; ++j)
        ob[(long)(mt+m0+i)*ldo + ot+o0+j] = 2.f*acc[i][j] - ni - nb[ot+o0+j];
    }
  } else {
    #pragma unroll
    for (int j = 0; j < 4; ++j){
      int o = ot + o0 + j;
      float s = gam[o]*BNF, sh = bet[o];
      float mv = -INFINITY;
      #pragma unroll
      for (int i = 0; i < 4; ++i){
        float y = acc[i][j]*s + sh;
        mv = fmaxf(mv, y >= 0.f ? y : 0.2f*y);
      }
      #pragma unroll
      for (int off = 8; off >= 1; off >>= 1)
        mv = fmaxf(mv, __shfl_xor(mv, off, 64));
      if (lm == 0) atomicMaxFloat(&pool[b*NPTS + o], mv);
    }
  }
}

// ---------------- gather-max ----------------
__global__ void k_gather(const float* __restrict__ UV, int ldUV,
                         const int* __restrict__ idx,
                         const float* __restrict__ gam, const float* __restrict__ bet,
                         float* __restrict__ out, int ldo, int O)
{
  int p = blockIdx.x;
  int b = p >> 10;
  int o = threadIdx.x;
  float u = UV[(long)p*ldUV + o];
  float v = UV[(long)p*ldUV + O + o];
  float base = v - u;
  float s = gam[o]*BNF, sh = bet[o];
  const int* ip = idx + p*KNN;
  const float* UVb = UV + (long)(b << 10)*ldUV;
  float best = -INFINITY;
  for (int k = 0; k < KNN; ++k){
    int j = ip[k];
    float y = (UVb[(long)j*ldUV + o] + base)*s + sh;
    best = fmaxf(best, y >= 0.f ? y : 0.2f*y);
  }
  out[(long)p*ldo + o] = best;
}

// ---------------- FC layers ----------------
__global__ void k_fc1(const float* __restrict__ p1, const float* __restrict__ p2,
                      const float* __restrict__ L1, const float* __restrict__ g6,
                      const float* __restrict__ b6, float* __restrict__ f1)
{
  __shared__ float fs[2048];
  int b = blockIdx.x, t = threadIdx.x;
  for (int s = 0; s < 4; ++s){
    int c = t + s*512;
    fs[c] = (c < 1024) ? p1[b*1024 + c] : p2[b*1024 + c - 1024];
  }
  __syncthreads();
  const float* w = L1 + (long)t*2048;
  float acc = 0.f;
  for (int c = 0; c < 2048; c += 4){
    float4 wv = *(const float4*)(w + c);
    acc += wv.x*fs[c] + wv.y*fs[c+1] + wv.z*fs[c+2] + wv.w*fs[c+3];
  }
  f1[b*512 + t] = leakyf(acc*g6[t]*BNF + b6[t]);
}

__global__ void k_fc2(const float* __restrict__ f1, const float* __restrict__ L2,
                      const float* __restrict__ bL2, const float* __restrict__ g7,
                      const float* __restrict__ b7, float* __restrict__ f2)
{
  __shared__ float fs[512];
  int b = blockIdx.x, t = threadIdx.x;
  fs[t] = f1[b*512 + t]; fs[t+256] = f1[b*512 + t + 256];
  __syncthreads();
  const float* w = L2 + (long)t*512;
  float acc = bL2[t];
  for (int c = 0; c < 512; c += 4){
    float4 wv = *(const float4*)(w + c);
    acc += wv.x*fs[c] + wv.y*fs[c+1] + wv.z*fs[c+2] + wv.w*fs[c+3];
  }
  f2[b*256 + t] = leakyf(acc*g7[t]*BNF + b7[t]);
}

__global__ void k_fc3(const float* __restrict__ f2, const float* __restrict__ L3,
                      const float* __restrict__ bL3, float* __restrict__ out)
{
  __shared__ float fs[256];
  int b = blockIdx.x, t = threadIdx.x;
  for (int s = 0; s < 4; ++s) fs[t + s*64] = f2[b*256 + t + s*64];
  __syncthreads();
  if (t < 40){
    const float* w = L3 + t*256;
    float acc = bL3[t];
    for (int c = 0; c < 256; c += 4){
      float4 wv = *(const float4*)(w + c);
      acc += wv.x*fs[c] + wv.y*fs[c+1] + wv.z*fs[c+2] + wv.w*fs[c+3];
    }
    out[b*40 + t] = acc;
  }
}

extern "C" void kernel_launch(void* const* d_in, const int* in_sizes, int n_in,
                              void* d_out, int out_size, void* d_ws, size_t ws_size,
                              hipStream_t stream) {
  const float* x   = (const float*)d_in[0];
  const float* W1  = (const float*)d_in[1];
  const float* g1  = (const float*)d_in[2];
  const float* b1  = (const float*)d_in[3];
  const float* W2  = (const float*)d_in[4];
  const float* g2  = (const float*)d_in[5];
  const float* b2  = (const float*)d_in[6];
  const float* W2m = (const float*)d_in[7];
  const float* g2m = (const float*)d_in[8];
  const float* b2m = (const float*)d_in[9];
  const float* W3  = (const float*)d_in[10];
  const float* g3  = (const float*)d_in[11];
  const float* b3  = (const float*)d_in[12];
  const float* W4  = (const float*)d_in[13];
  const float* g4  = (const float*)d_in[14];
  const float* b4  = (const float*)d_in[15];
  const float* W5  = (const float*)d_in[16];
  const float* g5  = (const float*)d_in[17];
  const float* b5  = (const float*)d_in[18];
  const float* L1  = (const float*)d_in[19];
  const float* g6  = (const float*)d_in[20];
  const float* b6  = (const float*)d_in[21];
  const float* L2  = (const float*)d_in[22];
  const float* bL2 = (const float*)d_in[23];
  const float* g7  = (const float*)d_in[24];
  const float* b7  = (const float*)d_in[25];
  const float* L3  = (const float*)d_in[26];
  const float* bL3 = (const float*)d_in[27];

  float* ws = (float*)d_ws;
  size_t off = 0;
  auto alloc = [&](size_t n)->float*{ float* p = ws + off; off += (n + 255) & ~(size_t)255; return p; };
  float* xt      = alloc((size_t)BATCH*NPTS*3);
  float* nrm     = alloc((size_t)BATCH*NPTS);
  float* D       = alloc((size_t)BATCH*NPTS*NPTS);
  int*   idx     = (int*)alloc((size_t)BATCH*NPTS*KNN);
  float* feat128 = alloc((size_t)BATCH*NPTS*128);
  float* UVbuf   = alloc((size_t)BATCH*NPTS*512);
  float* cat34   = alloc((size_t)BATCH*NPTS*512);
  float* W2p     = alloc(128*64);
  float* W3p     = alloc(512*128);
  float* W4p     = alloc(512*256);
  float* p1      = alloc((size_t)BATCH*1024);
  float* p2      = alloc((size_t)BATCH*1024);
  float* f1      = alloc((size_t)BATCH*512);
  float* f2      = alloc((size_t)BATCH*256);
  size_t baseNeed = off;

  auto ualloc = [&](size_t n_us)->unsigned short*{ return (unsigned short*)alloc((n_us + 1) / 2); };
  unsigned short* fh  = ualloc((size_t)BATCH*NPTS*128);
  unsigned short* fl  = ualloc((size_t)BATCH*NPTS*128);
  unsigned short* ch  = ualloc((size_t)BATCH*NPTS*512);
  unsigned short* cl  = ualloc((size_t)BATCH*NPTS*512);
  unsigned short* w2h = ualloc(128*64);
  unsigned short* w2l = ualloc(128*64);
  unsigned short* w3h = ualloc(512*128);
  unsigned short* w3l = ualloc(512*128);
  unsigned short* w4h = ualloc(512*256);
  unsigned short* w4l = ualloc(512*256);
  unsigned short* wmh = ualloc(1024*128);
  unsigned short* wml = ualloc(1024*128);
  unsigned short* w5h = ualloc(1024*512);
  unsigned short* w5l = ualloc(1024*512);

  if (baseNeed * sizeof(float) > ws_size) return;
  bool useMfma = (off * sizeof(float) <= ws_size);

  const long sF = (long)NPTS*128;
  const long sC = (long)NPTS*512;
  const long sD = (long)NPTS*NPTS;

  k_init<<<32, 256, 0, stream>>>(p1, p2);
  k_pack<<<800, 256, 0, stream>>>(W2, W3, W4, W2p, W3p, W4p);
  k_transpose<<<96, 256, 0, stream>>>(x, xt);

  // ---- EdgeConv 1 (C=3 -> 64) ----
  k_uv1<<<BATCH*NPTS, 128, 0, stream>>>(xt, W1, UVbuf);
  k_dist3<<<BATCH*NPTS, 256, 0, stream>>>(xt, D);
  k_topk<<<BATCH*NPTS/4, 256, 0, stream>>>(D, idx);
  k_gather<<<BATCH*NPTS, 64, 0, stream>>>(UVbuf, 128, idx, g1, b1, feat128, 128, 64);

  if (useMfma){
    // weight planes
    k_split<<<(128*64/4+255)/256,   256, 0, stream>>>(W2p, 64, 64,   128*64/4,   w2h, w2l);
    k_split<<<(512*128/4+255)/256,  256, 0, stream>>>(W3p, 128, 128, 512*128/4,  w3h, w3l);
    k_split<<<(512*256/4+255)/256,  256, 0, stream>>>(W4p, 256, 256, 512*256/4,  w4h, w4l);
    k_split<<<(1024*128/4+255)/256, 256, 0, stream>>>(W2m, 128, 128, 1024*128/4, wmh, wml);
    k_split<<<(1024*512/4+255)/256, 256, 0, stream>>>(W5,  512, 512, 1024*512/4, w5h, w5l);

    dim3 gD(8, 8, BATCH);
    // ---- EdgeConv 2 (C=64 -> 64) ----
    k_split<<<(8192*64/4)/256, 256, 0, stream>>>(feat128, 128, 64, 8192*64/4, fh, fl);
    k_norms<<<32, 256, 0, stream>>>(feat128, 128, 64, nrm);
    k_mgemm<1><<<gD, 256, 0, stream>>>(fh, fl, 128, sF, fh, fl, 128, sF, D, NPTS, sD, 64, nrm, nullptr, nullptr, nullptr);
    k_topk<<<BATCH*NPTS/4, 256, 0, stream>>>(D, idx);
    dim3 gUV2(8, 1, BATCH);
    k_mgemm<0><<<gUV2, 256, 0, stream>>>(fh, fl, 128, sF, w2h, w2l, 64, 0, UVbuf, 128, sF, 64, nullptr, nullptr, nullptr, nullptr);
    k_gather<<<BATCH*NPTS, 64, 0, stream>>>(UVbuf, 128, idx, g2, b2, feat128 + 64, 128, 64);

    // ---- EdgeConv 3 (folded: C=128 -> 256) ----
    k_split<<<(8192*64/4)/256, 256, 0, stream>>>(feat128 + 64, 128, 64, 8192*64/4, fh + 64, fl + 64);
    k_norms<<<32, 256, 0, stream>>>(feat128, 128, 128, nrm);
    k_mgemm<1><<<gD, 256, 0, stream>>>(fh, fl, 128, sF, fh, fl, 128, sF, D, NPTS, sD, 128, nrm, nullptr, nullptr, nullptr);
    k_topk<<<BATCH*NPTS/4, 256, 0, stream>>>(D, idx);
    dim3 gUV3(8, 4, BATCH);
    k_mgemm<0><<<gUV3, 256, 0, stream>>>(fh, fl, 128, sF, w3h, w3l, 128, 0, UVbuf, 512, sC, 128, nullptr, nullptr, nullptr, nullptr);
    k_gather<<<BATCH*NPTS, 256, 0, stream>>>(UVbuf, 512, idx, g3, b3, cat34, 512, 256);

    // ---- EdgeConv 4 (C=256 -> 256) ----
    k_split<<<(8192*256/4)/256, 256, 0, stream>>>(cat34, 512, 256, 8192*256/4, ch, cl);
    k_norms<<<32, 256, 0, stream>>>(cat34, 512, 256, nrm);
    k_mgemm<1><<<gD, 256, 0, stream>>>(ch, cl, 512, sC, ch, cl, 512, sC, D, NPTS, sD, 256, nrm, nullptr, nullptr, nullptr);
    k_topk<<<BATCH*NPTS/4, 256, 0, stream>>>(D, idx);
    k_mgemm<0><<<gUV3, 256, 0, stream>>>(ch, cl, 512, sC, w4h, w4l, 256, 0, UVbuf, 512, sC, 256, nullptr, nullptr, nullptr, nullptr);
    k_gather<<<BATCH*NPTS, 256, 0, stream>>>(UVbuf, 512, idx, g4, b4, cat34 + 256, 512, 256);

    // ---- fused pool projections ----
    k_split<<<(8192*256/4)/256, 256, 0, stream>>>(cat34 + 256, 512, 256, 8192*256/4, ch + 256, cl + 256);
    dim3 gP(8, 8, BATCH);
    k_mgemm<2><<<gP, 256, 0, stream>>>(fh, fl, 128, sF, wmh, wml, 128, 0, nullptr, 0, 0, 128, nullptr, g2m, b2m, p1);
    k_mgemm<2><<<gP, 256, 0, stream>>>(ch, cl, 512, sC, w5h, w5l, 512, 0, nullptr, 0, 0, 512, nullptr, g5, b5, p2);
  } else {
    dim3 gD(16, 16, BATCH);
    k_norms<<<32, 256, 0, stream>>>(feat128, 128, 64, nrm);
    k_gemm<1><<<gD, 256, 0, stream>>>(feat128, 128, sF, feat128, 128, sF, D, NPTS, sD, 64, nrm, nullptr, nullptr, nullptr);
    k_topk<<<BATCH*NPTS/4, 256, 0, stream>>>(D, idx);
    dim3 gUV2(16, 2, BATCH);
    k_gemm<0><<<gUV2, 256, 0, stream>>>(feat128, 128, sF, W2p, 64, 0, UVbuf, 128, sF, 64, nullptr, nullptr, nullptr, nullptr);
    k_gather<<<BATCH*NPTS, 64, 0, stream>>>(UVbuf, 128, idx, g2, b2, feat128 + 64, 128, 64);

    k_norms<<<32, 256, 0, stream>>>(feat128, 128, 128, nrm);
    k_gemm<1><<<gD, 256, 0, stream>>>(feat128, 128, sF, feat128, 128, sF, D, NPTS, sD, 128, nrm, nullptr, nullptr, nullptr);
    k_topk<<<BATCH*NPTS/4, 256, 0, stream>>>(D, idx);
    dim3 gUV3(16, 8, BATCH);
    k_gemm<0><<<gUV3, 256, 0, stream>>>(feat128, 128, sF, W3p, 128, 0, UVbuf, 512, sC, 128, nullptr, nullptr, nullptr, nullptr);
    k_gather<<<BATCH*NPTS, 256, 0, stream>>>(UVbuf, 512, idx, g3, b3, cat34, 512, 256);

    k_norms<<<32, 256, 0, stream>>>(cat34, 512, 256, nrm);
    k_gemm<1><<<gD, 256, 0, stream>>>(cat34, 512, sC, cat34, 512, sC, D, NPTS, sD, 256, nrm, nullptr, nullptr, nullptr);
    k_topk<<<BATCH*NPTS/4, 256, 0, stream>>>(D, idx);
    k_gemm<0><<<gUV3, 256, 0, stream>>>(cat34, 512, sC, W4p, 256, 0, UVbuf, 512, sC, 256, nullptr, nullptr, nullptr, nullptr);
    k_gather<<<BATCH*NPTS, 256, 0, stream>>>(UVbuf, 512, idx, g4, b4, cat34 + 256, 512, 256);

    dim3 gP(16, 16, BATCH);
    k_gemm<2><<<gP, 256, 0, stream>>>(feat128, 128, sF, W2m, 128, 0, nullptr, 0, 0, 128, nullptr, g2m, b2m, p1);
    k_gemm<2><<<gP, 256, 0, stream>>>(cat34, 512, sC, W5, 512, 0, nullptr, 0, 0, 512, nullptr, g5, b5, p2);
  }

  // ---- FC head ----
  k_fc1<<<BATCH, 512, 0, stream>>>(p1, p2, L1, g6, b6, f1);
  k_fc2<<<BATCH, 256, 0, stream>>>(f1, L2, bL2, g7, b7, f2);
  k_fc3<<<BATCH, 64, 0, stream>>>(f2, L3, bL3, (float*)d_out);
}

// Round 3
// 428.075 us; speedup vs baseline: 1.7006x; 1.2859x over previous
//
#include <hip/hip_runtime.h>
#include <math.h>

#define BATCH 8
#define NPTS  1024
#define KNN   20
#define BNF   0.99999500003749937f  // 1/sqrt(1+1e-5)

typedef short bf16x8 __attribute__((ext_vector_type(8)));
typedef float f32x4  __attribute__((ext_vector_type(4)));

__device__ __forceinline__ float leakyf(float x){ return x >= 0.f ? x : 0.2f*x; }

__device__ __forceinline__ void atomicMaxFloat(float* addr, float val){
  if (val >= 0.f) atomicMax((int*)addr, __float_as_int(val));
  else            atomicMin((unsigned int*)addr, __float_as_uint(val));
}

__device__ __forceinline__ unsigned short f2bf(float x){
  unsigned u = __float_as_uint(x);
  unsigned r = (u + 0x7FFFu + ((u >> 16) & 1u)) >> 16;   // RNE (no NaN/inf in data)
  return (unsigned short)r;
}
__device__ __forceinline__ float bf2f(unsigned short h){
  return __uint_as_float(((unsigned)h) << 16);
}

// ---------------- init p1/p2 to -inf ----------------
__global__ void k_init(float* p1, float* p2){
  int i = blockIdx.x*256 + threadIdx.x;
  if (i < BATCH*1024){ p1[i] = -INFINITY; p2[i] = -INFINITY; }
}

// ---------------- transpose x (B,3,N) -> xt (B,N,3) ----------------
__global__ void k_transpose(const float* __restrict__ x, float* __restrict__ xt){
  int gid = blockIdx.x*256 + threadIdx.x;
  if (gid >= BATCH*3*NPTS) return;
  int b = gid / (3*NPTS); int r = gid % (3*NPTS); int c = r / NPTS; int n = r % NPTS;
  xt[b*NPTS*3 + n*3 + c] = x[gid];
}

// ---------------- pack W2/W3/W4 into UV-stacked (and folded) form ----------------
__global__ void k_pack(const float* __restrict__ W2, const float* __restrict__ W3,
                       const float* __restrict__ W4,
                       float* __restrict__ W2p, float* __restrict__ W3p, float* __restrict__ W4p){
  int gid = blockIdx.x*256 + threadIdx.x;
  if (gid < 128*64){
    int o = gid / 64, c = gid % 64;
    W2p[gid] = (o < 64) ? W2[o*128 + c] : W2[(o-64)*128 + 64 + c];
  }
  int g3 = gid - 128*64;
  if (g3 >= 0 && g3 < 512*128){
    int o = g3 / 128, c = g3 % 128;
    W3p[g3] = (o < 256) ? (W3[o*512 + c]        + W3[o*512 + 128 + c])
                        : (W3[(o-256)*512 + 256 + c] + W3[(o-256)*512 + 384 + c]);
  }
  int g4 = gid - 128*64 - 512*128;
  if (g4 >= 0 && g4 < 512*256){
    int o = g4 / 256, c = g4 % 256;
    W4p[g4] = (o < 256) ? W4[o*512 + c] : W4[(o-256)*512 + 256 + c];
  }
}

// ---------------- split f32 -> bf16 hi/lo planes (same ld) ----------------
__global__ void k_split(const float* __restrict__ src, int ld, int cols, int total4,
                        unsigned short* __restrict__ hi, unsigned short* __restrict__ lo){
  int i = blockIdx.x*256 + threadIdx.x;
  if (i >= total4) return;
  int c4 = cols >> 2;
  int r = i / c4, c = (i % c4) * 4;
  const float* s = src + (long)r*ld + c;
  float4 v = *(const float4*)s;
  unsigned short h0 = f2bf(v.x), h1 = f2bf(v.y), h2 = f2bf(v.z), h3 = f2bf(v.w);
  unsigned short l0 = f2bf(v.x - bf2f(h0));
  unsigned short l1 = f2bf(v.y - bf2f(h1));
  unsigned short l2 = f2bf(v.z - bf2f(h2));
  unsigned short l3 = f2bf(v.w - bf2f(h3));
  *(ushort4*)(hi + (long)r*ld + c) = make_ushort4(h0, h1, h2, h3);
  *(ushort4*)(lo + (long)r*ld + c) = make_ushort4(l0, l1, l2, l3);
}

// ---------------- EC1 U/V (K=3), out (B*N,128) = [U(64)|V(64)] ----------------
__global__ void k_uv1(const float* __restrict__ xt, const float* __restrict__ W1,
                      float* __restrict__ UV){
  int p = blockIdx.x;
  int o = threadIdx.x;
  const float* xp = xt + p*3;
  float x0 = xp[0], x1 = xp[1], x2 = xp[2];
  const float* w = (o < 64) ? (W1 + o*6) : (W1 + (o-64)*6 + 3);
  UV[(long)p*128 + o] = w[0]*x0 + w[1]*x1 + w[2]*x2;
}

// ---------------- neg pairwise sq-dist, C=3 ----------------
__global__ void k_dist3(const float* __restrict__ xt, float* __restrict__ D){
  int p = blockIdx.x; int b = p >> 10; int i = p & 1023;
  const float* base = xt + (long)b*NPTS*3;
  float x0 = base[i*3], x1 = base[i*3+1], x2 = base[i*3+2];
  float* Drow = D + (long)p*NPTS;
  for (int s = 0; s < 4; ++s){
    int j = threadIdx.x + s*256;
    float d0 = x0 - base[j*3], d1 = x1 - base[j*3+1], d2 = x2 - base[j*3+2];
    Drow[j] = -(d0*d0 + d1*d1 + d2*d2);
  }
}

// ---------------- row squared norms (f32 exact) ----------------
__global__ void k_norms(const float* __restrict__ A, int lda, int C, float* __restrict__ nrm){
  int p = blockIdx.x*256 + threadIdx.x;
  if (p >= BATCH*NPTS) return;
  const float* a = A + (long)p*lda;
  float s = 0.f;
  for (int c = 0; c < C; c += 4){
    float4 v = *(const float4*)(a + c);
    s += v.x*v.x; s += v.y*v.y; s += v.z*v.z; s += v.w*v.w;
  }
  nrm[p] = s;
}

// ---------------- top-20 per row (max value, lowest index) ----------------
__global__ void k_topk(const float* __restrict__ D, int* __restrict__ idx){
  int w = threadIdx.x >> 6;
  int lane = threadIdx.x & 63;
  int row = blockIdx.x*4 + w;
  const float* Drow = D + (long)row*NPTS;
  float v[16];
  #pragma unroll
  for (int m = 0; m < 16; ++m) v[m] = Drow[m*64 + lane];
  int* out = idx + row*KNN;
  for (int it = 0; it < KNN; ++it){
    float bv = -INFINITY; int bi = NPTS;
    #pragma unroll
    for (int m = 0; m < 16; ++m){
      if (v[m] > bv){ bv = v[m]; bi = m*64 + lane; }
    }
    #pragma unroll
    for (int off = 32; off >= 1; off >>= 1){
      float ov = __shfl_xor(bv, off, 64);
      int   oi = __shfl_xor(bi, off, 64);
      if (ov > bv || (ov == bv && oi < bi)){ bv = ov; bi = oi; }
    }
    if (lane == 0) out[it] = bi;
    if ((bi & 63) == lane){
      int slot = bi >> 6;
      #pragma unroll
      for (int m = 0; m < 16; ++m) if (m == slot) v[m] = -INFINITY;
    }
  }
}

// =====================================================================
// split-bf16 MFMA GEMM: OUT(M x N) = A(M x K) * Bm(N x K)^T  (3-term hi/lo)
// block 128x128, 4 waves of 64x64, K-step 32.
// POST 0: store. POST 1: D = 2*acc - nrm[i] - nrm[j]. POST 2: bn+leaky+max_M -> pool
// =====================================================================
template<int POST>
__launch_bounds__(256)
__global__ void k_mgemm(const unsigned short* __restrict__ Ah, const unsigned short* __restrict__ Al,
                        int lda, long sA,
                        const unsigned short* __restrict__ Bh, const unsigned short* __restrict__ Bl,
                        int ldb, long sB,
                        float* __restrict__ out, int ldo, long sO, int Ktot,
                        const float* __restrict__ nrm,
                        const float* __restrict__ gam, const float* __restrict__ bet,
                        float* __restrict__ pool)
{
  __shared__ unsigned short As[2][128*32];
  __shared__ unsigned short Bs[2][128*32];
  int b = blockIdx.z;
  int mt = blockIdx.x*128, ot = blockIdx.y*128;
  const unsigned short* pA0 = Ah + (long)b*sA;
  const unsigned short* pA1 = Al + (long)b*sA;
  const unsigned short* pB0 = Bh + (long)b*sB;
  const unsigned short* pB1 = Bl + (long)b*sB;
  int t = threadIdx.x;
  int lane = t & 63, w = t >> 6;
  int wm = w >> 1, wn = w & 1;
  int frow = lane & 15, kg = lane >> 4;

  f32x4 acc[4][4] = {};

  int srow = t >> 2;
  int q    = t & 3;

  for (int k0 = 0; k0 < Ktot; k0 += 32){
    __syncthreads();
    #pragma unroll
    for (int it = 0; it < 4; ++it){
      const int plane = it >> 1;
      const int row = (it & 1)*64 + srow;
      const unsigned short* gA = (plane ? pA1 : pA0) + (long)(mt+row)*lda + k0 + q*8;
      const unsigned short* gB = (plane ? pB1 : pB0) + (long)(ot+row)*ldb + k0 + q*8;
      uint4 va = *(const uint4*)gA;
      uint4 vb = *(const uint4*)gB;
      int loff = row*32 + ((q ^ (row & 3))*8);
      *(uint4*)&As[plane][loff] = va;
      *(uint4*)&Bs[plane][loff] = vb;
    }
    __syncthreads();

    bf16x8 af[2][4], bfr[2][4];
    #pragma unroll
    for (int p = 0; p < 2; ++p){
      #pragma unroll
      for (int mi = 0; mi < 4; ++mi){
        int row = wm*64 + mi*16 + frow;
        af[p][mi] = *(const bf16x8*)&As[p][row*32 + ((kg ^ (row & 3))*8)];
      }
      #pragma unroll
      for (int ni = 0; ni < 4; ++ni){
        int row = wn*64 + ni*16 + frow;
        bfr[p][ni] = *(const bf16x8*)&Bs[p][row*32 + ((kg ^ (row & 3))*8)];
      }
    }
    #pragma unroll
    for (int mi = 0; mi < 4; ++mi){
      #pragma unroll
      for (int ni = 0; ni < 4; ++ni){
        acc[mi][ni] = __builtin_amdgcn_mfma_f32_16x16x32_bf16(af[0][mi], bfr[0][ni], acc[mi][ni], 0, 0, 0);
        acc[mi][ni] = __builtin_amdgcn_mfma_f32_16x16x32_bf16(af[0][mi], bfr[1][ni], acc[mi][ni], 0, 0, 0);
        acc[mi][ni] = __builtin_amdgcn_mfma_f32_16x16x32_bf16(af[1][mi], bfr[0][ni], acc[mi][ni], 0, 0, 0);
      }
    }
  }

  if (POST == 0){
    float* ob = out + (long)b*sO;
    #pragma unroll
    for (int mi = 0; mi < 4; ++mi){
      int grow0 = mt + wm*64 + mi*16 + kg*4;
      #pragma unroll
      for (int ni = 0; ni < 4; ++ni){
        int gcol = ot + wn*64 + ni*16 + frow;
        #pragma unroll
        for (int j = 0; j < 4; ++j)
          ob[(long)(grow0+j)*ldo + gcol] = acc[mi][ni][j];
      }
    }
  } else if (POST == 1){
    const float* nb = nrm + b*NPTS;
    float* ob = out + (long)b*sO;
    #pragma unroll
    for (int mi = 0; mi < 4; ++mi){
      int grow0 = mt + wm*64 + mi*16 + kg*4;
      #pragma unroll
      for (int ni = 0; ni < 4; ++ni){
        int gcol = ot + wn*64 + ni*16 + frow;
        float nj = nb[gcol];
        #pragma unroll
        for (int j = 0; j < 4; ++j)
          ob[(long)(grow0+j)*ldo + gcol] = 2.f*acc[mi][ni][j] - nb[grow0+j] - nj;
      }
    }
  } else {
    #pragma unroll
    for (int ni = 0; ni < 4; ++ni){
      int o = ot + wn*64 + ni*16 + frow;
      float s = gam[o]*BNF, sh = bet[o];
      float mv = -INFINITY;
      #pragma unroll
      for (int mi = 0; mi < 4; ++mi){
        #pragma unroll
        for (int j = 0; j < 4; ++j){
          float y = acc[mi][ni][j]*s + sh;
          mv = fmaxf(mv, y >= 0.f ? y : 0.2f*y);
        }
      }
      mv = fmaxf(mv, __shfl_xor(mv, 16, 64));
      mv = fmaxf(mv, __shfl_xor(mv, 32, 64));
      if (lane < 16) atomicMaxFloat(&pool[b*NPTS + o], mv);
    }
  }
}

// ---------------- gather-max ----------------
__global__ void k_gather(const float* __restrict__ UV, int ldUV,
                         const int* __restrict__ idx,
                         const float* __restrict__ gam, const float* __restrict__ bet,
                         float* __restrict__ out, int ldo, int O)
{
  int p = blockIdx.x;
  int b = p >> 10;
  int o = threadIdx.x;
  float u = UV[(long)p*ldUV + o];
  float v = UV[(long)p*ldUV + O + o];
  float base = v - u;
  float s = gam[o]*BNF, sh = bet[o];
  const int* ip = idx + p*KNN;
  const float* UVb = UV + (long)(b << 10)*ldUV;
  float best = -INFINITY;
  for (int k = 0; k < KNN; ++k){
    int j = ip[k];
    float y = (UVb[(long)j*ldUV + o] + base)*s + sh;
    best = fmaxf(best, y >= 0.f ? y : 0.2f*y);
  }
  out[(long)p*ldo + o] = best;
}

// ---------------- FC layers: one wave per output row, all 8 batches ----------------
// f = [p1 | p2] (2048). grid 128 blocks x 256 thr.
__global__ void k_fc1(const float* __restrict__ p1, const float* __restrict__ p2,
                      const float* __restrict__ L1, const float* __restrict__ g6,
                      const float* __restrict__ b6, float* __restrict__ f1)
{
  int t = threadIdx.x;
  int lane = t & 63;
  int o = blockIdx.x*4 + (t >> 6);
  const float* w = L1 + (long)o*2048;
  float acc[BATCH] = {};
  for (int c0 = lane*4; c0 < 2048; c0 += 256){
    float4 wv = *(const float4*)(w + c0);
    const float* fb = (c0 < 1024) ? (p1 + c0) : (p2 + c0 - 1024);
    #pragma unroll
    for (int b = 0; b < BATCH; ++b){
      float4 fv = *(const float4*)(fb + b*1024);
      acc[b] += wv.x*fv.x + wv.y*fv.y + wv.z*fv.z + wv.w*fv.w;
    }
  }
  float s = g6[o]*BNF, sh = b6[o];
  #pragma unroll
  for (int b = 0; b < BATCH; ++b){
    float a = acc[b];
    #pragma unroll
    for (int off = 32; off >= 1; off >>= 1) a += __shfl_xor(a, off, 64);
    if (lane == b) f1[b*512 + o] = leakyf(a*s + sh);
  }
}

// grid 64 blocks x 256 thr; wave per output (256 outputs), K=512 (8 floats/lane)
__global__ void k_fc2(const float* __restrict__ f1, const float* __restrict__ L2,
                      const float* __restrict__ bL2, const float* __restrict__ g7,
                      const float* __restrict__ b7, float* __restrict__ f2)
{
  int t = threadIdx.x;
  int lane = t & 63;
  int o = blockIdx.x*4 + (t >> 6);
  const float* w = L2 + (long)o*512 + lane*8;
  float4 w0 = *(const float4*)w;
  float4 w1 = *(const float4*)(w + 4);
  float s = g7[o]*BNF, sh = bL2[o]*g7[o]*BNF + b7[o];
  #pragma unroll
  for (int b = 0; b < BATCH; ++b){
    const float* fb = f1 + b*512 + lane*8;
    float4 f0 = *(const float4*)fb;
    float4 f1v = *(const float4*)(fb + 4);
    float a = w0.x*f0.x + w0.y*f0.y + w0.z*f0.z + w0.w*f0.w
            + w1.x*f1v.x + w1.y*f1v.y + w1.z*f1v.z + w1.w*f1v.w;
    #pragma unroll
    for (int off = 32; off >= 1; off >>= 1) a += __shfl_xor(a, off, 64);
    if (lane == b) f2[b*256 + o] = leakyf(a*s + sh);
  }
}

// grid 40 blocks x 64 thr; wave per output, K=256 (4 floats/lane)
__global__ void k_fc3(const float* __restrict__ f2, const float* __restrict__ L3,
                      const float* __restrict__ bL3, float* __restrict__ out)
{
  int lane = threadIdx.x;
  int o = blockIdx.x;
  float4 wv = *(const float4*)(L3 + (long)o*256 + lane*4);
  float bias = bL3[o];
  #pragma unroll
  for (int b = 0; b < BATCH; ++b){
    float4 fv = *(const float4*)(f2 + b*256 + lane*4);
    float a = wv.x*fv.x + wv.y*fv.y + wv.z*fv.z + wv.w*fv.w;
    #pragma unroll
    for (int off = 32; off >= 1; off >>= 1) a += __shfl_xor(a, off, 64);
    if (lane == b) out[b*40 + o] = a + bias;
  }
}

extern "C" void kernel_launch(void* const* d_in, const int* in_sizes, int n_in,
                              void* d_out, int out_size, void* d_ws, size_t ws_size,
                              hipStream_t stream) {
  const float* x   = (const float*)d_in[0];
  const float* W1  = (const float*)d_in[1];
  const float* g1  = (const float*)d_in[2];
  const float* b1  = (const float*)d_in[3];
  const float* W2  = (const float*)d_in[4];
  const float* g2  = (const float*)d_in[5];
  const float* b2  = (const float*)d_in[6];
  const float* W2m = (const float*)d_in[7];
  const float* g2m = (const float*)d_in[8];
  const float* b2m = (const float*)d_in[9];
  const float* W3  = (const float*)d_in[10];
  const float* g3  = (const float*)d_in[11];
  const float* b3  = (const float*)d_in[12];
  const float* W4  = (const float*)d_in[13];
  const float* g4  = (const float*)d_in[14];
  const float* b4  = (const float*)d_in[15];
  const float* W5  = (const float*)d_in[16];
  const float* g5  = (const float*)d_in[17];
  const float* b5  = (const float*)d_in[18];
  const float* L1  = (const float*)d_in[19];
  const float* g6  = (const float*)d_in[20];
  const float* b6  = (const float*)d_in[21];
  const float* L2  = (const float*)d_in[22];
  const float* bL2 = (const float*)d_in[23];
  const float* g7  = (const float*)d_in[24];
  const float* b7  = (const float*)d_in[25];
  const float* L3  = (const float*)d_in[26];
  const float* bL3 = (const float*)d_in[27];

  float* ws = (float*)d_ws;
  size_t off = 0;
  auto alloc = [&](size_t n)->float*{ float* p = ws + off; off += (n + 255) & ~(size_t)255; return p; };
  float* xt      = alloc((size_t)BATCH*NPTS*3);
  float* nrm     = alloc((size_t)BATCH*NPTS);
  float* D       = alloc((size_t)BATCH*NPTS*NPTS);
  int*   idx     = (int*)alloc((size_t)BATCH*NPTS*KNN);
  float* feat128 = alloc((size_t)BATCH*NPTS*128);
  float* UVbuf   = alloc((size_t)BATCH*NPTS*512);
  float* cat34   = alloc((size_t)BATCH*NPTS*512);
  float* W2p     = alloc(128*64);
  float* W3p     = alloc(512*128);
  float* W4p     = alloc(512*256);
  float* p1      = alloc((size_t)BATCH*1024);
  float* p2      = alloc((size_t)BATCH*1024);
  float* f1      = alloc((size_t)BATCH*512);
  float* f2      = alloc((size_t)BATCH*256);
  size_t baseNeed = off;

  auto ualloc = [&](size_t n_us)->unsigned short*{ return (unsigned short*)alloc((n_us + 1) / 2); };
  unsigned short* fh  = ualloc((size_t)BATCH*NPTS*128);
  unsigned short* fl  = ualloc((size_t)BATCH*NPTS*128);
  unsigned short* ch  = ualloc((size_t)BATCH*NPTS*512);
  unsigned short* cl  = ualloc((size_t)BATCH*NPTS*512);
  unsigned short* w2h = ualloc(128*64);
  unsigned short* w2l = ualloc(128*64);
  unsigned short* w3h = ualloc(512*128);
  unsigned short* w3l = ualloc(512*128);
  unsigned short* w4h = ualloc(512*256);
  unsigned short* w4l = ualloc(512*256);
  unsigned short* wmh = ualloc(1024*128);
  unsigned short* wml = ualloc(1024*128);
  unsigned short* w5h = ualloc(1024*512);
  unsigned short* w5l = ualloc(1024*512);

  if (baseNeed * sizeof(float) > ws_size) return;
  bool useMfma = (off * sizeof(float) <= ws_size);

  const long sF = (long)NPTS*128;
  const long sC = (long)NPTS*512;
  const long sD = (long)NPTS*NPTS;

  k_init<<<32, 256, 0, stream>>>(p1, p2);
  k_pack<<<800, 256, 0, stream>>>(W2, W3, W4, W2p, W3p, W4p);
  k_transpose<<<96, 256, 0, stream>>>(x, xt);

  // ---- EdgeConv 1 (C=3 -> 64) ----
  k_uv1<<<BATCH*NPTS, 128, 0, stream>>>(xt, W1, UVbuf);
  k_dist3<<<BATCH*NPTS, 256, 0, stream>>>(xt, D);
  k_topk<<<BATCH*NPTS/4, 256, 0, stream>>>(D, idx);
  k_gather<<<BATCH*NPTS, 64, 0, stream>>>(UVbuf, 128, idx, g1, b1, feat128, 128, 64);

  if (useMfma){
    // weight planes
    k_split<<<(128*64/4+255)/256,   256, 0, stream>>>(W2p, 64, 64,   128*64/4,   w2h, w2l);
    k_split<<<(512*128/4+255)/256,  256, 0, stream>>>(W3p, 128, 128, 512*128/4,  w3h, w3l);
    k_split<<<(512*256/4+255)/256,  256, 0, stream>>>(W4p, 256, 256, 512*256/4,  w4h, w4l);
    k_split<<<(1024*128/4+255)/256, 256, 0, stream>>>(W2m, 128, 128, 1024*128/4, wmh, wml);
    k_split<<<(1024*512/4+255)/256, 256, 0, stream>>>(W5,  512, 512, 1024*512/4, w5h, w5l);

    dim3 gD(8, 8, BATCH);
    // ---- EdgeConv 2 (C=64 -> 64) ----
    k_split<<<(8192*64/4)/256, 256, 0, stream>>>(feat128, 128, 64, 8192*64/4, fh, fl);
    k_norms<<<32, 256, 0, stream>>>(feat128, 128, 64, nrm);
    k_mgemm<1><<<gD, 256, 0, stream>>>(fh, fl, 128, sF, fh, fl, 128, sF, D, NPTS, sD, 64, nrm, nullptr, nullptr, nullptr);
    k_topk<<<BATCH*NPTS/4, 256, 0, stream>>>(D, idx);
    dim3 gUV2(8, 1, BATCH);
    k_mgemm<0><<<gUV2, 256, 0, stream>>>(fh, fl, 128, sF, w2h, w2l, 64, 0, UVbuf, 128, sF, 64, nullptr, nullptr, nullptr, nullptr);
    k_gather<<<BATCH*NPTS, 64, 0, stream>>>(UVbuf, 128, idx, g2, b2, feat128 + 64, 128, 64);

    // ---- EdgeConv 3 (folded: C=128 -> 256) ----
    k_split<<<(8192*64/4)/256, 256, 0, stream>>>(feat128 + 64, 128, 64, 8192*64/4, fh + 64, fl + 64);
    k_norms<<<32, 256, 0, stream>>>(feat128, 128, 128, nrm);
    k_mgemm<1><<<gD, 256, 0, stream>>>(fh, fl, 128, sF, fh, fl, 128, sF, D, NPTS, sD, 128, nrm, nullptr, nullptr, nullptr);
    k_topk<<<BATCH*NPTS/4, 256, 0, stream>>>(D, idx);
    dim3 gUV3(8, 4, BATCH);
    k_mgemm<0><<<gUV3, 256, 0, stream>>>(fh, fl, 128, sF, w3h, w3l, 128, 0, UVbuf, 512, sC, 128, nullptr, nullptr, nullptr, nullptr);
    k_gather<<<BATCH*NPTS, 256, 0, stream>>>(UVbuf, 512, idx, g3, b3, cat34, 512, 256);

    // ---- EdgeConv 4 (C=256 -> 256) ----
    k_split<<<(8192*256/4)/256, 256, 0, stream>>>(cat34, 512, 256, 8192*256/4, ch, cl);
    k_norms<<<32, 256, 0, stream>>>(cat34, 512, 256, nrm);
    k_mgemm<1><<<gD, 256, 0, stream>>>(ch, cl, 512, sC, ch, cl, 512, sC, D, NPTS, sD, 256, nrm, nullptr, nullptr, nullptr);
    k_topk<<<BATCH*NPTS/4, 256, 0, stream>>>(D, idx);
    k_mgemm<0><<<gUV3, 256, 0, stream>>>(ch, cl, 512, sC, w4h, w4l, 256, 0, UVbuf, 512, sC, 256, nullptr, nullptr, nullptr, nullptr);
    k_gather<<<BATCH*NPTS, 256, 0, stream>>>(UVbuf, 512, idx, g4, b4, cat34 + 256, 512, 256);

    // ---- fused pool projections ----
    k_split<<<(8192*256/4)/256, 256, 0, stream>>>(cat34 + 256, 512, 256, 8192*256/4, ch + 256, cl + 256);
    dim3 gP(8, 8, BATCH);
    k_mgemm<2><<<gP, 256, 0, stream>>>(fh, fl, 128, sF, wmh, wml, 128, 0, nullptr, 0, 0, 128, nullptr, g2m, b2m, p1);
    k_mgemm<2><<<gP, 256, 0, stream>>>(ch, cl, 512, sC, w5h, w5l, 512, 0, nullptr, 0, 0, 512, nullptr, g5, b5, p2);
  } else {
    // (f32 fallback omitted for ws-rich harness; requires useMfma)
    return;
  }

  // ---- FC head ----
  k_fc1<<<128, 256, 0, stream>>>(p1, p2, L1, g6, b6, f1);
  k_fc2<<<64, 256, 0, stream>>>(f1, L2, bL2, g7, b7, f2);
  k_fc3<<<40, 64, 0, stream>>>(f2, L3, bL3, (float*)d_out);
}

// Round 4
// 339.823 us; speedup vs baseline: 2.1423x; 1.2597x over previous
//
#include <hip/hip_runtime.h>
#include <math.h>

#define BATCH 8
#define NPTS  1024
#define KNN   20
#define BNF   0.99999500003749937f  // 1/sqrt(1+1e-5)

typedef short bf16x8 __attribute__((ext_vector_type(8)));
typedef float f32x4  __attribute__((ext_vector_type(4)));

__device__ __forceinline__ float leakyf(float x){ return x >= 0.f ? x : 0.2f*x; }

__device__ __forceinline__ void atomicMaxFloat(float* addr, float val){
  if (val >= 0.f) atomicMax((int*)addr, __float_as_int(val));
  else            atomicMin((unsigned int*)addr, __float_as_uint(val));
}

__device__ __forceinline__ unsigned short f2bf(float x){
  unsigned u = __float_as_uint(x);
  unsigned r = (u + 0x7FFFu + ((u >> 16) & 1u)) >> 16;   // RNE (no NaN/inf in data)
  return (unsigned short)r;
}
__device__ __forceinline__ float bf2f(unsigned short h){
  return __uint_as_float(((unsigned)h) << 16);
}

// monotone f32 -> u32 key (exact order-preserving)
__device__ __forceinline__ unsigned ordkey(float x){
  unsigned u = __float_as_uint(x);
  unsigned mask = (unsigned)(((int)u) >> 31) | 0x80000000u;
  return u ^ mask;
}

// ---------------- init p1/p2 to -inf ----------------
__global__ void k_init(float* p1, float* p2){
  int i = blockIdx.x*256 + threadIdx.x;
  if (i < BATCH*1024){ p1[i] = -INFINITY; p2[i] = -INFINITY; }
}

// ---------------- transpose x (B,3,N) -> xt (B,N,3) ----------------
__global__ void k_transpose(const float* __restrict__ x, float* __restrict__ xt){
  int gid = blockIdx.x*256 + threadIdx.x;
  if (gid >= BATCH*3*NPTS) return;
  int b = gid / (3*NPTS); int r = gid % (3*NPTS); int c = r / NPTS; int n = r % NPTS;
  xt[b*NPTS*3 + n*3 + c] = x[gid];
}

// ---------------- pack W2/W3/W4 into UV-stacked (and folded) form ----------------
__global__ void k_pack(const float* __restrict__ W2, const float* __restrict__ W3,
                       const float* __restrict__ W4,
                       float* __restrict__ W2p, float* __restrict__ W3p, float* __restrict__ W4p){
  int gid = blockIdx.x*256 + threadIdx.x;
  if (gid < 128*64){
    int o = gid / 64, c = gid % 64;
    W2p[gid] = (o < 64) ? W2[o*128 + c] : W2[(o-64)*128 + 64 + c];
  }
  int g3 = gid - 128*64;
  if (g3 >= 0 && g3 < 512*128){
    int o = g3 / 128, c = g3 % 128;
    W3p[g3] = (o < 256) ? (W3[o*512 + c]        + W3[o*512 + 128 + c])
                        : (W3[(o-256)*512 + 256 + c] + W3[(o-256)*512 + 384 + c]);
  }
  int g4 = gid - 128*64 - 512*128;
  if (g4 >= 0 && g4 < 512*256){
    int o = g4 / 256, c = g4 % 256;
    W4p[g4] = (o < 256) ? W4[o*512 + c] : W4[(o-256)*512 + 256 + c];
  }
}

// ---------------- split f32 -> bf16 hi/lo planes (weights only now) ----------------
__global__ void k_split(const float* __restrict__ src, int ld, int cols, int total4,
                        unsigned short* __restrict__ hi, unsigned short* __restrict__ lo){
  int i = blockIdx.x*256 + threadIdx.x;
  if (i >= total4) return;
  int c4 = cols >> 2;
  int r = i / c4, c = (i % c4) * 4;
  const float* s = src + (long)r*ld + c;
  float4 v = *(const float4*)s;
  unsigned short h0 = f2bf(v.x), h1 = f2bf(v.y), h2 = f2bf(v.z), h3 = f2bf(v.w);
  unsigned short l0 = f2bf(v.x - bf2f(h0));
  unsigned short l1 = f2bf(v.y - bf2f(h1));
  unsigned short l2 = f2bf(v.z - bf2f(h2));
  unsigned short l3 = f2bf(v.w - bf2f(h3));
  *(ushort4*)(hi + (long)r*ld + c) = make_ushort4(h0, h1, h2, h3);
  *(ushort4*)(lo + (long)r*ld + c) = make_ushort4(l0, l1, l2, l3);
}

// ---------------- EC1 U/V (K=3), out (B*N,128) = [U(64)|V(64)] ----------------
__global__ void k_uv1(const float* __restrict__ xt, const float* __restrict__ W1,
                      float* __restrict__ UV){
  int p = blockIdx.x;
  int o = threadIdx.x;
  const float* xp = xt + p*3;
  float x0 = xp[0], x1 = xp[1], x2 = xp[2];
  const float* w = (o < 64) ? (W1 + o*6) : (W1 + (o-64)*6 + 3);
  UV[(long)p*128 + o] = w[0]*x0 + w[1]*x1 + w[2]*x2;
}

// ---------------- row squared norms (f32 exact) ----------------
__global__ void k_norms(const float* __restrict__ A, int lda, int C, float* __restrict__ nrm){
  int p = blockIdx.x*256 + threadIdx.x;
  if (p >= BATCH*NPTS) return;
  const float* a = A + (long)p*lda;
  float s = 0.f;
  for (int c = 0; c < C; c += 4){
    float4 v = *(const float4*)(a + c);
    s += v.x*v.x; s += v.y*v.y; s += v.z*v.z; s += v.w*v.w;
  }
  nrm[p] = s;
}

// ================= top-20 selection (exact: value desc, index asc) =================
// lane-major: lane owns elements [lane*16, lane*16+16). Keys sorted once per lane,
// spilled to wave-private LDS column; per-iter DPP wave-max + ballot + prefetch.

__device__ __forceinline__ unsigned wave_max_u32(unsigned x){
  unsigned t;
  t = (unsigned)__builtin_amdgcn_update_dpp((int)x, (int)x, 0x111, 0xf, 0xf, false); x = x > t ? x : t;
  t = (unsigned)__builtin_amdgcn_update_dpp((int)x, (int)x, 0x112, 0xf, 0xf, false); x = x > t ? x : t;
  t = (unsigned)__builtin_amdgcn_update_dpp((int)x, (int)x, 0x114, 0xf, 0xf, false); x = x > t ? x : t;
  t = (unsigned)__builtin_amdgcn_update_dpp((int)x, (int)x, 0x118, 0xf, 0xf, false); x = x > t ? x : t;
  t = (unsigned)__builtin_amdgcn_update_dpp((int)x, (int)x, 0x142, 0xa, 0xf, false); x = x > t ? x : t;
  t = (unsigned)__builtin_amdgcn_update_dpp((int)x, (int)x, 0x143, 0xc, 0xf, false); x = x > t ? x : t;
  return (unsigned)__builtin_amdgcn_readlane((int)x, 63);
}

__device__ __forceinline__ void topk_select(unsigned long long* sk,      // 16 keys: (ordval<<4)|(15-slot)
                                            unsigned long long* lds,    // [18*64] wave-private
                                            int* __restrict__ out, int lane)
{
  // Batcher odd-even mergesort, 16 elems, descending (63 CEs, all static indices)
  #define CE(a,b) { unsigned long long ka=sk[a], kb=sk[b]; bool sw=ka<kb; sk[a]=sw?kb:ka; sk[b]=sw?ka:kb; }
  CE(0,1) CE(2,3) CE(4,5) CE(6,7) CE(8,9) CE(10,11) CE(12,13) CE(14,15)
  CE(0,2) CE(1,3) CE(4,6) CE(5,7) CE(8,10) CE(9,11) CE(12,14) CE(13,15)
  CE(1,2) CE(5,6) CE(9,10) CE(13,14)
  CE(0,4) CE(1,5) CE(2,6) CE(3,7) CE(8,12) CE(9,13) CE(10,14) CE(11,15)
  CE(2,4) CE(3,5) CE(10,12) CE(11,13)
  CE(1,2) CE(3,4) CE(5,6) CE(9,10) CE(11,12) CE(13,14)
  CE(0,8) CE(1,9) CE(2,10) CE(3,11) CE(4,12) CE(5,13) CE(6,14) CE(7,15)
  CE(4,8) CE(5,9) CE(6,10) CE(7,11)
  CE(2,4) CE(3,5) CE(6,8) CE(7,9) CE(10,12) CE(11,13)
  CE(1,2) CE(3,4) CE(5,6) CE(7,8) CE(9,10) CE(11,12) CE(13,14)
  #undef CE

  // spill sorted list to own LDS column: entry = (slot<<32)|key
  #pragma unroll
  for (int m = 0; m < 16; ++m){
    unsigned key = (unsigned)(sk[m] >> 4);
    unsigned slot = 15u - ((unsigned)sk[m] & 15u);
    lds[m*64 + lane] = ((unsigned long long)slot << 32) | (unsigned long long)key;
  }
  lds[16*64 + lane] = 0ull;   // sentinels (key 0 < any real key)
  lds[17*64 + lane] = 0ull;

  unsigned hk = (unsigned)(sk[0] >> 4); int hs = 15 - (int)((unsigned)sk[0] & 15u);
  unsigned nk = (unsigned)(sk[1] >> 4); int ns = 15 - (int)((unsigned)sk[1] & 15u);
  int p = 2;

  #pragma unroll
  for (int it = 0; it < KNN; ++it){
    unsigned g = wave_max_u32(hk);
    unsigned long long mask = __ballot(hk == g);
    int wl = __ffsll((long long)mask) - 1;          // lowest lane = lowest index
    int ws = __builtin_amdgcn_readlane(hs, wl);
    if (lane == 0) out[it] = wl*16 + ws;
    bool win = ((int)lane == wl);
    hk = win ? nk : hk;
    hs = win ? ns : hs;
    if (win){
      unsigned long long e = lds[p*64 + lane];
      nk = (unsigned)e; ns = (int)(e >> 32);
      p++;
    }
  }
}

// EC1: fused distance (C=3) + select. 1 wave per row.
__global__ __launch_bounds__(256) void k_topk1(const float* __restrict__ xt, int* __restrict__ idx){
  __shared__ unsigned long long lds[4][18*64];
  int t = threadIdx.x, lane = t & 63, w = t >> 6;
  int row = blockIdx.x*4 + w;
  int b = row >> 10, i0 = row & 1023;
  const float* base = xt + (long)b*NPTS*3;
  float cx = base[i0*3], cy = base[i0*3+1], cz = base[i0*3+2];
  float pts[48];
  #pragma unroll
  for (int q = 0; q < 12; ++q)
    *(float4*)&pts[q*4] = *(const float4*)&base[lane*48 + q*4];
  unsigned long long sk[16];
  #pragma unroll
  for (int m = 0; m < 16; ++m){
    float dx = pts[m*3]-cx, dy = pts[m*3+1]-cy, dz = pts[m*3+2]-cz;
    float d = -(dx*dx + dy*dy + dz*dz);
    sk[m] = ((unsigned long long)ordkey(d) << 4) | (unsigned long long)(15 - m);
  }
  topk_select(sk, lds[w], idx + row*KNN, lane);
}

// EC2-4: read D row, select. 1 wave per row.
__global__ __launch_bounds__(256) void k_topkD(const float* __restrict__ D, int* __restrict__ idx){
  __shared__ unsigned long long lds[4][18*64];
  int t = threadIdx.x, lane = t & 63, w = t >> 6;
  int row = blockIdx.x*4 + w;
  const float* Dr = D + (long)row*NPTS + lane*16;
  float v[16];
  #pragma unroll
  for (int q = 0; q < 4; ++q)
    *(float4*)&v[q*4] = *(const float4*)&Dr[q*4];
  unsigned long long sk[16];
  #pragma unroll
  for (int m = 0; m < 16; ++m)
    sk[m] = ((unsigned long long)ordkey(v[m]) << 4) | (unsigned long long)(15 - m);
  topk_select(sk, lds[w], idx + row*KNN, lane);
}

// =====================================================================
// split-bf16 MFMA GEMM: OUT(M x N) = A(M x K) * Bm(N x K)^T  (3-term hi/lo)
// block 128x128, 4 waves of 64x64, K-step 32.
// POST 0: store. POST 1: D = 2*acc - nrm[i] - nrm[j]. POST 2: bn+leaky+max_M -> pool
// =====================================================================
template<int POST>
__launch_bounds__(256)
__global__ void k_mgemm(const unsigned short* __restrict__ Ah, const unsigned short* __restrict__ Al,
                        int lda, long sA,
                        const unsigned short* __restrict__ Bh, const unsigned short* __restrict__ Bl,
                        int ldb, long sB,
                        float* __restrict__ out, int ldo, long sO, int Ktot,
                        const float* __restrict__ nrm,
                        const float* __restrict__ gam, const float* __restrict__ bet,
                        float* __restrict__ pool)
{
  __shared__ unsigned short As[2][128*32];
  __shared__ unsigned short Bs[2][128*32];
  int b = blockIdx.z;
  int mt = blockIdx.x*128, ot = blockIdx.y*128;
  const unsigned short* pA0 = Ah + (long)b*sA;
  const unsigned short* pA1 = Al + (long)b*sA;
  const unsigned short* pB0 = Bh + (long)b*sB;
  const unsigned short* pB1 = Bl + (long)b*sB;
  int t = threadIdx.x;
  int lane = t & 63, w = t >> 6;
  int wm = w >> 1, wn = w & 1;
  int frow = lane & 15, kg = lane >> 4;

  f32x4 acc[4][4] = {};

  int srow = t >> 2;
  int q    = t & 3;

  for (int k0 = 0; k0 < Ktot; k0 += 32){
    __syncthreads();
    #pragma unroll
    for (int it = 0; it < 4; ++it){
      const int plane = it >> 1;
      const int row = (it & 1)*64 + srow;
      const unsigned short* gA = (plane ? pA1 : pA0) + (long)(mt+row)*lda + k0 + q*8;
      const unsigned short* gB = (plane ? pB1 : pB0) + (long)(ot+row)*ldb + k0 + q*8;
      uint4 va = *(const uint4*)gA;
      uint4 vb = *(const uint4*)gB;
      int loff = row*32 + ((q ^ (row & 3))*8);
      *(uint4*)&As[plane][loff] = va;
      *(uint4*)&Bs[plane][loff] = vb;
    }
    __syncthreads();

    bf16x8 af[2][4], bfr[2][4];
    #pragma unroll
    for (int p = 0; p < 2; ++p){
      #pragma unroll
      for (int mi = 0; mi < 4; ++mi){
        int row = wm*64 + mi*16 + frow;
        af[p][mi] = *(const bf16x8*)&As[p][row*32 + ((kg ^ (row & 3))*8)];
      }
      #pragma unroll
      for (int ni = 0; ni < 4; ++ni){
        int row = wn*64 + ni*16 + frow;
        bfr[p][ni] = *(const bf16x8*)&Bs[p][row*32 + ((kg ^ (row & 3))*8)];
      }
    }
    #pragma unroll
    for (int mi = 0; mi < 4; ++mi){
      #pragma unroll
      for (int ni = 0; ni < 4; ++ni){
        acc[mi][ni] = __builtin_amdgcn_mfma_f32_16x16x32_bf16(af[0][mi], bfr[0][ni], acc[mi][ni], 0, 0, 0);
        acc[mi][ni] = __builtin_amdgcn_mfma_f32_16x16x32_bf16(af[0][mi], bfr[1][ni], acc[mi][ni], 0, 0, 0);
        acc[mi][ni] = __builtin_amdgcn_mfma_f32_16x16x32_bf16(af[1][mi], bfr[0][ni], acc[mi][ni], 0, 0, 0);
      }
    }
  }

  if (POST == 0){
    float* ob = out + (long)b*sO;
    #pragma unroll
    for (int mi = 0; mi < 4; ++mi){
      int grow0 = mt + wm*64 + mi*16 + kg*4;
      #pragma unroll
      for (int ni = 0; ni < 4; ++ni){
        int gcol = ot + wn*64 + ni*16 + frow;
        #pragma unroll
        for (int j = 0; j < 4; ++j)
          ob[(long)(grow0+j)*ldo + gcol] = acc[mi][ni][j];
      }
    }
  } else if (POST == 1){
    const float* nb = nrm + b*NPTS;
    float* ob = out + (long)b*sO;
    #pragma unroll
    for (int mi = 0; mi < 4; ++mi){
      int grow0 = mt + wm*64 + mi*16 + kg*4;
      #pragma unroll
      for (int ni = 0; ni < 4; ++ni){
        int gcol = ot + wn*64 + ni*16 + frow;
        float nj = nb[gcol];
        #pragma unroll
        for (int j = 0; j < 4; ++j)
          ob[(long)(grow0+j)*ldo + gcol] = 2.f*acc[mi][ni][j] - nb[grow0+j] - nj;
      }
    }
  } else {
    #pragma unroll
    for (int ni = 0; ni < 4; ++ni){
      int o = ot + wn*64 + ni*16 + frow;
      float s = gam[o]*BNF, sh = bet[o];
      float mv = -INFINITY;
      #pragma unroll
      for (int mi = 0; mi < 4; ++mi){
        #pragma unroll
        for (int j = 0; j < 4; ++j){
          float y = acc[mi][ni][j]*s + sh;
          mv = fmaxf(mv, y >= 0.f ? y : 0.2f*y);
        }
      }
      mv = fmaxf(mv, __shfl_xor(mv, 16, 64));
      mv = fmaxf(mv, __shfl_xor(mv, 32, 64));
      if (lane < 16) atomicMaxFloat(&pool[b*NPTS + o], mv);
    }
  }
}

// ---------------- gather-max + fused bf16 hi/lo split of the output ----------------
template<int O>
__global__ void k_gather(const float* __restrict__ UV, int ldUV,
                         const int* __restrict__ idx,
                         const float* __restrict__ gam, const float* __restrict__ bet,
                         float* __restrict__ out, int ldo,
                         unsigned short* __restrict__ oh, unsigned short* __restrict__ ol)
{
  constexpr int PPB = 256 / O;
  int t = threadIdx.x;
  int p = blockIdx.x*PPB + t/O;
  int o = t % O;
  int b = p >> 10;
  float u = UV[(long)p*ldUV + o];
  float v = UV[(long)p*ldUV + O + o];
  float base = v - u;
  float s = gam[o]*BNF, sh = bet[o];
  const int* ip = idx + p*KNN;
  const float* UVb = UV + (long)(b << 10)*ldUV;
  float best = -INFINITY;
  for (int k = 0; k < KNN; ++k){
    int j = ip[k];
    float y = (UVb[(long)j*ldUV + o] + base)*s + sh;
    best = fmaxf(best, y >= 0.f ? y : 0.2f*y);
  }
  long oo = (long)p*ldo + o;
  out[oo] = best;
  unsigned short h = f2bf(best);
  oh[oo] = h;
  ol[oo] = f2bf(best - bf2f(h));
}

// ---------------- FC layers: one wave per output row, all 8 batches ----------------
__global__ void k_fc1(const float* __restrict__ p1, const float* __restrict__ p2,
                      const float* __restrict__ L1, const float* __restrict__ g6,
                      const float* __restrict__ b6, float* __restrict__ f1)
{
  int t = threadIdx.x;
  int lane = t & 63;
  int o = blockIdx.x*4 + (t >> 6);
  const float* w = L1 + (long)o*2048;
  float acc[BATCH] = {};
  for (int c0 = lane*4; c0 < 2048; c0 += 256){
    float4 wv = *(const float4*)(w + c0);
    const float* fb = (c0 < 1024) ? (p1 + c0) : (p2 + c0 - 1024);
    #pragma unroll
    for (int b = 0; b < BATCH; ++b){
      float4 fv = *(const float4*)(fb + b*1024);
      acc[b] += wv.x*fv.x + wv.y*fv.y + wv.z*fv.z + wv.w*fv.w;
    }
  }
  float s = g6[o]*BNF, sh = b6[o];
  #pragma unroll
  for (int b = 0; b < BATCH; ++b){
    float a = acc[b];
    #pragma unroll
    for (int off = 32; off >= 1; off >>= 1) a += __shfl_xor(a, off, 64);
    if (lane == b) f1[b*512 + o] = leakyf(a*s + sh);
  }
}

__global__ void k_fc2(const float* __restrict__ f1, const float* __restrict__ L2,
                      const float* __restrict__ bL2, const float* __restrict__ g7,
                      const float* __restrict__ b7, float* __restrict__ f2)
{
  int t = threadIdx.x;
  int lane = t & 63;
  int o = blockIdx.x*4 + (t >> 6);
  const float* w = L2 + (long)o*512 + lane*8;
  float4 w0 = *(const float4*)w;
  float4 w1 = *(const float4*)(w + 4);
  float s = g7[o]*BNF, sh = bL2[o]*g7[o]*BNF + b7[o];
  #pragma unroll
  for (int b = 0; b < BATCH; ++b){
    const float* fb = f1 + b*512 + lane*8;
    float4 f0 = *(const float4*)fb;
    float f1v0 = fb[4], f1v1 = fb[5], f1v2 = fb[6], f1v3 = fb[7];
    float a = w0.x*f0.x + w0.y*f0.y + w0.z*f0.z + w0.w*f0.w
            + w1.x*f1v0 + w1.y*f1v1 + w1.z*f1v2 + w1.w*f1v3;
    #pragma unroll
    for (int off = 32; off >= 1; off >>= 1) a += __shfl_xor(a, off, 64);
    if (lane == b) f2[b*256 + o] = leakyf(a*s + sh);
  }
}

__global__ void k_fc3(const float* __restrict__ f2, const float* __restrict__ L3,
                      const float* __restrict__ bL3, float* __restrict__ out)
{
  int lane = threadIdx.x;
  int o = blockIdx.x;
  float4 wv = *(const float4*)(L3 + (long)o*256 + lane*4);
  float bias = bL3[o];
  #pragma unroll
  for (int b = 0; b < BATCH; ++b){
    float4 fv = *(const float4*)(f2 + b*256 + lane*4);
    float a = wv.x*fv.x + wv.y*fv.y + wv.z*fv.z + wv.w*fv.w;
    #pragma unroll
    for (int off = 32; off >= 1; off >>= 1) a += __shfl_xor(a, off, 64);
    if (lane == b) out[b*40 + o] = a + bias;
  }
}

extern "C" void kernel_launch(void* const* d_in, const int* in_sizes, int n_in,
                              void* d_out, int out_size, void* d_ws, size_t ws_size,
                              hipStream_t stream) {
  const float* x   = (const float*)d_in[0];
  const float* W1  = (const float*)d_in[1];
  const float* g1  = (const float*)d_in[2];
  const float* b1  = (const float*)d_in[3];
  const float* W2  = (const float*)d_in[4];
  const float* g2  = (const float*)d_in[5];
  const float* b2  = (const float*)d_in[6];
  const float* W2m = (const float*)d_in[7];
  const float* g2m = (const float*)d_in[8];
  const float* b2m = (const float*)d_in[9];
  const float* W3  = (const float*)d_in[10];
  const float* g3  = (const float*)d_in[11];
  const float* b3  = (const float*)d_in[12];
  const float* W4  = (const float*)d_in[13];
  const float* g4  = (const float*)d_in[14];
  const float* b4  = (const float*)d_in[15];
  const float* W5  = (const float*)d_in[16];
  const float* g5  = (const float*)d_in[17];
  const float* b5  = (const float*)d_in[18];
  const float* L1  = (const float*)d_in[19];
  const float* g6  = (const float*)d_in[20];
  const float* b6  = (const float*)d_in[21];
  const float* L2  = (const float*)d_in[22];
  const float* bL2 = (const float*)d_in[23];
  const float* g7  = (const float*)d_in[24];
  const float* b7  = (const float*)d_in[25];
  const float* L3  = (const float*)d_in[26];
  const float* bL3 = (const float*)d_in[27];

  float* ws = (float*)d_ws;
  size_t off = 0;
  auto alloc = [&](size_t n)->float*{ float* p = ws + off; off += (n + 255) & ~(size_t)255; return p; };
  float* xt      = alloc((size_t)BATCH*NPTS*3);
  float* nrm     = alloc((size_t)BATCH*NPTS);
  float* D       = alloc((size_t)BATCH*NPTS*NPTS);
  int*   idx     = (int*)alloc((size_t)BATCH*NPTS*KNN);
  float* feat128 = alloc((size_t)BATCH*NPTS*128);
  float* UVbuf   = alloc((size_t)BATCH*NPTS*512);
  float* cat34   = alloc((size_t)BATCH*NPTS*512);
  float* W2p     = alloc(128*64);
  float* W3p     = alloc(512*128);
  float* W4p     = alloc(512*256);
  float* p1      = alloc((size_t)BATCH*1024);
  float* p2      = alloc((size_t)BATCH*1024);
  float* f1      = alloc((size_t)BATCH*512);
  float* f2      = alloc((size_t)BATCH*256);

  auto ualloc = [&](size_t n_us)->unsigned short*{ return (unsigned short*)alloc((n_us + 1) / 2); };
  unsigned short* fh  = ualloc((size_t)BATCH*NPTS*128);
  unsigned short* fl  = ualloc((size_t)BATCH*NPTS*128);
  unsigned short* ch  = ualloc((size_t)BATCH*NPTS*512);
  unsigned short* cl  = ualloc((size_t)BATCH*NPTS*512);
  unsigned short* w2h = ualloc(128*64);
  unsigned short* w2l = ualloc(128*64);
  unsigned short* w3h = ualloc(512*128);
  unsigned short* w3l = ualloc(512*128);
  unsigned short* w4h = ualloc(512*256);
  unsigned short* w4l = ualloc(512*256);
  unsigned short* wmh = ualloc(1024*128);
  unsigned short* wml = ualloc(1024*128);
  unsigned short* w5h = ualloc(1024*512);
  unsigned short* w5l = ualloc(1024*512);

  if (off * sizeof(float) > ws_size) return;  // insufficient workspace -> fail loudly

  const long sF = (long)NPTS*128;
  const long sC = (long)NPTS*512;
  const long sD = (long)NPTS*NPTS;

  k_init<<<32, 256, 0, stream>>>(p1, p2);
  k_pack<<<800, 256, 0, stream>>>(W2, W3, W4, W2p, W3p, W4p);
  k_transpose<<<96, 256, 0, stream>>>(x, xt);

  // weight planes
  k_split<<<(128*64/4+255)/256,   256, 0, stream>>>(W2p, 64, 64,   128*64/4,   w2h, w2l);
  k_split<<<(512*128/4+255)/256,  256, 0, stream>>>(W3p, 128, 128, 512*128/4,  w3h, w3l);
  k_split<<<(512*256/4+255)/256,  256, 0, stream>>>(W4p, 256, 256, 512*256/4,  w4h, w4l);
  k_split<<<(1024*128/4+255)/256, 256, 0, stream>>>(W2m, 128, 128, 1024*128/4, wmh, wml);
  k_split<<<(1024*512/4+255)/256, 256, 0, stream>>>(W5,  512, 512, 1024*512/4, w5h, w5l);

  // ---- EdgeConv 1 (C=3 -> 64), distance fused into topk ----
  k_uv1<<<BATCH*NPTS, 128, 0, stream>>>(xt, W1, UVbuf);
  k_topk1<<<BATCH*NPTS/4, 256, 0, stream>>>(xt, idx);
  k_gather<64><<<BATCH*NPTS/4, 256, 0, stream>>>(UVbuf, 128, idx, g1, b1, feat128, 128, fh, fl);

  dim3 gD(8, 8, BATCH);
  // ---- EdgeConv 2 (C=64 -> 64) ----
  k_norms<<<32, 256, 0, stream>>>(feat128, 128, 64, nrm);
  k_mgemm<1><<<gD, 256, 0, stream>>>(fh, fl, 128, sF, fh, fl, 128, sF, D, NPTS, sD, 64, nrm, nullptr, nullptr, nullptr);
  k_topkD<<<BATCH*NPTS/4, 256, 0, stream>>>(D, idx);
  dim3 gUV2(8, 1, BATCH);
  k_mgemm<0><<<gUV2, 256, 0, stream>>>(fh, fl, 128, sF, w2h, w2l, 64, 0, UVbuf, 128, sF, 64, nullptr, nullptr, nullptr, nullptr);
  k_gather<64><<<BATCH*NPTS/4, 256, 0, stream>>>(UVbuf, 128, idx, g2, b2, feat128 + 64, 128, fh + 64, fl + 64);

  // ---- EdgeConv 3 (folded: C=128 -> 256) ----
  k_norms<<<32, 256, 0, stream>>>(feat128, 128, 128, nrm);
  k_mgemm<1><<<gD, 256, 0, stream>>>(fh, fl, 128, sF, fh, fl, 128, sF, D, NPTS, sD, 128, nrm, nullptr, nullptr, nullptr);
  k_topkD<<<BATCH*NPTS/4, 256, 0, stream>>>(D, idx);
  dim3 gUV3(8, 4, BATCH);
  k_mgemm<0><<<gUV3, 256, 0, stream>>>(fh, fl, 128, sF, w3h, w3l, 128, 0, UVbuf, 512, sC, 128, nullptr, nullptr, nullptr, nullptr);
  k_gather<256><<<BATCH*NPTS, 256, 0, stream>>>(UVbuf, 512, idx, g3, b3, cat34, 512, ch, cl);

  // ---- EdgeConv 4 (C=256 -> 256) ----
  k_norms<<<32, 256, 0, stream>>>(cat34, 512, 256, nrm);
  k_mgemm<1><<<gD, 256, 0, stream>>>(ch, cl, 512, sC, ch, cl, 512, sC, D, NPTS, sD, 256, nrm, nullptr, nullptr, nullptr);
  k_topkD<<<BATCH*NPTS/4, 256, 0, stream>>>(D, idx);
  k_mgemm<0><<<gUV3, 256, 0, stream>>>(ch, cl, 512, sC, w4h, w4l, 256, 0, UVbuf, 512, sC, 256, nullptr, nullptr, nullptr, nullptr);
  k_gather<256><<<BATCH*NPTS, 256, 0, stream>>>(UVbuf, 512, idx, g4, b4, cat34 + 256, 512, ch + 256, cl + 256);

  // ---- fused pool projections ----
  dim3 gP(8, 8, BATCH);
  k_mgemm<2><<<gP, 256, 0, stream>>>(fh, fl, 128, sF, wmh, wml, 128, 0, nullptr, 0, 0, 128, nullptr, g2m, b2m, p1);
  k_mgemm<2><<<gP, 256, 0, stream>>>(ch, cl, 512, sC, w5h, w5l, 512, 0, nullptr, 0, 0, 512, nullptr, g5, b5, p2);

  // ---- FC head ----
  k_fc1<<<128, 256, 0, stream>>>(p1, p2, L1, g6, b6, f1);
  k_fc2<<<64, 256, 0, stream>>>(f1, L2, bL2, g7, b7, f2);
  k_fc3<<<40, 64, 0, stream>>>(f2, L3, bL3, (float*)d_out);
}

// Round 5
// 309.664 us; speedup vs baseline: 2.3509x; 1.0974x over previous
//
#include <hip/hip_runtime.h>
#include <math.h>

#define BATCH 8
#define NPTS  1024
#define KNN   20
#define BNF   0.99999500003749937f  // 1/sqrt(1+1e-5)

typedef short bf16x8 __attribute__((ext_vector_type(8)));
typedef float f32x4  __attribute__((ext_vector_type(4)));

__device__ __forceinline__ float leakyf(float x){ return x >= 0.f ? x : 0.2f*x; }

__device__ __forceinline__ void atomicMaxFloat(float* addr, float val){
  if (val >= 0.f) atomicMax((int*)addr, __float_as_int(val));
  else            atomicMin((unsigned int*)addr, __float_as_uint(val));
}

__device__ __forceinline__ unsigned short f2bf(float x){
  unsigned u = __float_as_uint(x);
  unsigned r = (u + 0x7FFFu + ((u >> 16) & 1u)) >> 16;   // RNE (no NaN/inf in data)
  return (unsigned short)r;
}
__device__ __forceinline__ float bf2f(unsigned short h){
  return __uint_as_float(((unsigned)h) << 16);
}

// monotone f32 -> u32 key (exact order-preserving)
__device__ __forceinline__ unsigned ordkey(float x){
  unsigned u = __float_as_uint(x);
  unsigned mask = (unsigned)(((int)u) >> 31) | 0x80000000u;
  return u ^ mask;
}

// =====================================================================
// k_prep: ONE kernel for all weight pack+split, pool init, x transpose.
// Work in 4-element units; section sizes:
//  S1 W2 pack+split   : 2048    (128x64)
//  S2 W3 fold+split   : 16384   (512x128)
//  S3 W4 pack+split   : 32768   (512x256)
//  S4 W2m split       : 32768   (1024x128)
//  S5 W5 split        : 131072  (1024x512)
//  S6 p1/p2 init      : 4096
//  S7 x transpose     : 6144
// total 225280 units = 880 blocks x 256
// =====================================================================
__device__ __forceinline__ void split4store(float v0, float v1, float v2, float v3,
                                            unsigned short* hi, unsigned short* lo, long off){
  unsigned short h0=f2bf(v0), h1=f2bf(v1), h2=f2bf(v2), h3=f2bf(v3);
  *(ushort4*)(hi+off) = make_ushort4(h0,h1,h2,h3);
  *(ushort4*)(lo+off) = make_ushort4(f2bf(v0-bf2f(h0)), f2bf(v1-bf2f(h1)),
                                     f2bf(v2-bf2f(h2)), f2bf(v3-bf2f(h3)));
}

__global__ __launch_bounds__(256) void k_prep(
    const float* __restrict__ x,  const float* __restrict__ W2,
    const float* __restrict__ W3, const float* __restrict__ W4,
    const float* __restrict__ W2m,const float* __restrict__ W5,
    unsigned short* __restrict__ w2h, unsigned short* __restrict__ w2l,
    unsigned short* __restrict__ w3h, unsigned short* __restrict__ w3l,
    unsigned short* __restrict__ w4h, unsigned short* __restrict__ w4l,
    unsigned short* __restrict__ wmh, unsigned short* __restrict__ wml,
    unsigned short* __restrict__ w5h, unsigned short* __restrict__ w5l,
    float* __restrict__ p1, float* __restrict__ p2, float* __restrict__ xt)
{
  int u = blockIdx.x*256 + threadIdx.x;
  if (u < 2048){                                   // S1: W2p
    int o = u >> 4, c = (u & 15) * 4;
    const float* s = (o < 64) ? (W2 + o*128 + c) : (W2 + (o-64)*128 + 64 + c);
    float4 v = *(const float4*)s;
    split4store(v.x,v.y,v.z,v.w, w2h,w2l, (long)o*64 + c);
    return;
  }
  u -= 2048;
  if (u < 16384){                                  // S2: W3p (folded)
    int o = u >> 5, c = (u & 31) * 4;
    const float* s = (o < 256) ? (W3 + o*512 + c) : (W3 + (o-256)*512 + 256 + c);
    float4 a = *(const float4*)s;
    float4 b = *(const float4*)(s + 128);
    split4store(a.x+b.x, a.y+b.y, a.z+b.z, a.w+b.w, w3h,w3l, (long)o*128 + c);
    return;
  }
  u -= 16384;
  if (u < 32768){                                  // S3: W4p
    int o = u >> 6, c = (u & 63) * 4;
    const float* s = (o < 256) ? (W4 + o*512 + c) : (W4 + (o-256)*512 + 256 + c);
    float4 v = *(const float4*)s;
    split4store(v.x,v.y,v.z,v.w, w4h,w4l, (long)o*256 + c);
    return;
  }
  u -= 32768;
  if (u < 32768){                                  // S4: W2m
    int r = u >> 5, c = (u & 31) * 4;
    float4 v = *(const float4*)(W2m + (long)r*128 + c);
    split4store(v.x,v.y,v.z,v.w, wmh,wml, (long)r*128 + c);
    return;
  }
  u -= 32768;
  if (u < 131072){                                 // S5: W5
    int r = u >> 7, c = (u & 127) * 4;
    float4 v = *(const float4*)(W5 + (long)r*512 + c);
    split4store(v.x,v.y,v.z,v.w, w5h,w5l, (long)r*512 + c);
    return;
  }
  u -= 131072;
  if (u < 4096){                                   // S6: pool init
    float4 ninf = make_float4(-INFINITY,-INFINITY,-INFINITY,-INFINITY);
    if (u < 2048) *(float4*)(p1 + u*4) = ninf;
    else          *(float4*)(p2 + (u-2048)*4) = ninf;
    return;
  }
  u -= 4096;
  {                                                // S7: transpose x -> xt
    int b = u / 768, rem = u % 768;
    int c = rem >> 8, n0 = (rem & 255) * 4;
    float4 v = *(const float4*)(x + ((long)b*3 + c)*NPTS + n0);
    float* o = xt + (long)b*NPTS*3;
    o[(n0+0)*3 + c] = v.x; o[(n0+1)*3 + c] = v.y;
    o[(n0+2)*3 + c] = v.z; o[(n0+3)*3 + c] = v.w;
  }
}

// ---------------- EC1 U/V (K=3), out (B*N,128) = [U(64)|V(64)] ----------------
__global__ void k_uv1(const float* __restrict__ xt, const float* __restrict__ W1,
                      float* __restrict__ UV){
  int p = blockIdx.x;
  int o = threadIdx.x;
  const float* xp = xt + p*3;
  float x0 = xp[0], x1 = xp[1], x2 = xp[2];
  const float* w = (o < 64) ? (W1 + o*6) : (W1 + (o-64)*6 + 3);
  UV[(long)p*128 + o] = w[0]*x0 + w[1]*x1 + w[2]*x2;
}

// ================= top-20 selection (exact: value desc, index asc) =================
__device__ __forceinline__ unsigned wave_max_u32(unsigned x){
  unsigned t;
  t = (unsigned)__builtin_amdgcn_update_dpp((int)x, (int)x, 0x111, 0xf, 0xf, false); x = x > t ? x : t;
  t = (unsigned)__builtin_amdgcn_update_dpp((int)x, (int)x, 0x112, 0xf, 0xf, false); x = x > t ? x : t;
  t = (unsigned)__builtin_amdgcn_update_dpp((int)x, (int)x, 0x114, 0xf, 0xf, false); x = x > t ? x : t;
  t = (unsigned)__builtin_amdgcn_update_dpp((int)x, (int)x, 0x118, 0xf, 0xf, false); x = x > t ? x : t;
  t = (unsigned)__builtin_amdgcn_update_dpp((int)x, (int)x, 0x142, 0xa, 0xf, false); x = x > t ? x : t;
  t = (unsigned)__builtin_amdgcn_update_dpp((int)x, (int)x, 0x143, 0xc, 0xf, false); x = x > t ? x : t;
  return (unsigned)__builtin_amdgcn_readlane((int)x, 63);
}

__device__ __forceinline__ void topk_select(unsigned long long* sk,
                                            unsigned long long* lds,
                                            int* __restrict__ out, int lane)
{
  #define CE(a,b) { unsigned long long ka=sk[a], kb=sk[b]; bool sw=ka<kb; sk[a]=sw?kb:ka; sk[b]=sw?ka:kb; }
  CE(0,1) CE(2,3) CE(4,5) CE(6,7) CE(8,9) CE(10,11) CE(12,13) CE(14,15)
  CE(0,2) CE(1,3) CE(4,6) CE(5,7) CE(8,10) CE(9,11) CE(12,14) CE(13,15)
  CE(1,2) CE(5,6) CE(9,10) CE(13,14)
  CE(0,4) CE(1,5) CE(2,6) CE(3,7) CE(8,12) CE(9,13) CE(10,14) CE(11,15)
  CE(2,4) CE(3,5) CE(10,12) CE(11,13)
  CE(1,2) CE(3,4) CE(5,6) CE(9,10) CE(11,12) CE(13,14)
  CE(0,8) CE(1,9) CE(2,10) CE(3,11) CE(4,12) CE(5,13) CE(6,14) CE(7,15)
  CE(4,8) CE(5,9) CE(6,10) CE(7,11)
  CE(2,4) CE(3,5) CE(6,8) CE(7,9) CE(10,12) CE(11,13)
  CE(1,2) CE(3,4) CE(5,6) CE(7,8) CE(9,10) CE(11,12) CE(13,14)
  #undef CE

  #pragma unroll
  for (int m = 0; m < 16; ++m){
    unsigned key = (unsigned)(sk[m] >> 4);
    unsigned slot = 15u - ((unsigned)sk[m] & 15u);
    lds[m*64 + lane] = ((unsigned long long)slot << 32) | (unsigned long long)key;
  }
  lds[16*64 + lane] = 0ull;
  lds[17*64 + lane] = 0ull;

  unsigned hk = (unsigned)(sk[0] >> 4); int hs = 15 - (int)((unsigned)sk[0] & 15u);
  unsigned nk = (unsigned)(sk[1] >> 4); int ns = 15 - (int)((unsigned)sk[1] & 15u);
  int p = 2;

  #pragma unroll
  for (int it = 0; it < KNN; ++it){
    unsigned g = wave_max_u32(hk);
    unsigned long long mask = __ballot(hk == g);
    int wl = __ffsll((long long)mask) - 1;
    int ws = __builtin_amdgcn_readlane(hs, wl);
    if (lane == 0) out[it] = wl*16 + ws;
    bool win = ((int)lane == wl);
    hk = win ? nk : hk;
    hs = win ? ns : hs;
    if (win){
      unsigned long long e = lds[p*64 + lane];
      nk = (unsigned)e; ns = (int)(e >> 32);
      p++;
    }
  }
}

__global__ __launch_bounds__(256) void k_topk1(const float* __restrict__ xt, int* __restrict__ idx){
  __shared__ unsigned long long lds[4][18*64];
  int t = threadIdx.x, lane = t & 63, w = t >> 6;
  int row = blockIdx.x*4 + w;
  int b = row >> 10, i0 = row & 1023;
  const float* base = xt + (long)b*NPTS*3;
  float cx = base[i0*3], cy = base[i0*3+1], cz = base[i0*3+2];
  float pts[48];
  #pragma unroll
  for (int q = 0; q < 12; ++q)
    *(float4*)&pts[q*4] = *(const float4*)&base[lane*48 + q*4];
  unsigned long long sk[16];
  #pragma unroll
  for (int m = 0; m < 16; ++m){
    float dx = pts[m*3]-cx, dy = pts[m*3+1]-cy, dz = pts[m*3+2]-cz;
    float d = -(dx*dx + dy*dy + dz*dz);
    sk[m] = ((unsigned long long)ordkey(d) << 4) | (unsigned long long)(15 - m);
  }
  topk_select(sk, lds[w], idx + row*KNN, lane);
}

__global__ __launch_bounds__(256) void k_topkD(const float* __restrict__ D, int* __restrict__ idx){
  __shared__ unsigned long long lds[4][18*64];
  int t = threadIdx.x, lane = t & 63, w = t >> 6;
  int row = blockIdx.x*4 + w;
  const float* Dr = D + (long)row*NPTS + lane*16;
  float v[16];
  #pragma unroll
  for (int q = 0; q < 4; ++q)
    *(float4*)&v[q*4] = *(const float4*)&Dr[q*4];
  unsigned long long sk[16];
  #pragma unroll
  for (int m = 0; m < 16; ++m)
    sk[m] = ((unsigned long long)ordkey(v[m]) << 4) | (unsigned long long)(15 - m);
  topk_select(sk, lds[w], idx + row*KNN, lane);
}

// =====================================================================
// split-bf16 MFMA GEMM. POST 0: store. POST 1: symmetric distance
// (triangular grid of 36 tiles, mirror-write). POST 2: bn+leaky+max_M.
// =====================================================================
template<int POST>
__launch_bounds__(256)
__global__ void k_mgemm(const unsigned short* __restrict__ Ah, const unsigned short* __restrict__ Al,
                        int lda, long sA,
                        const unsigned short* __restrict__ Bh, const unsigned short* __restrict__ Bl,
                        int ldb, long sB,
                        float* __restrict__ out, int ldo, long sO, int Ktot,
                        const float* __restrict__ nrm,
                        const float* __restrict__ gam, const float* __restrict__ bet,
                        float* __restrict__ pool)
{
  __shared__ unsigned short As[2][128*32];
  __shared__ unsigned short Bs[2][128*32];
  int b = blockIdx.z;
  int mt, ot;
  if (POST == 1){
    int u = blockIdx.x, r = 0;
    while (u >= 8 - r){ u -= 8 - r; ++r; }       // triangular decode: bi=r <= bj
    mt = r*128; ot = (r + u)*128;
  } else {
    mt = blockIdx.x*128; ot = blockIdx.y*128;
  }
  const unsigned short* pA0 = Ah + (long)b*sA;
  const unsigned short* pA1 = Al + (long)b*sA;
  const unsigned short* pB0 = Bh + (long)b*sB;
  const unsigned short* pB1 = Bl + (long)b*sB;
  int t = threadIdx.x;
  int lane = t & 63, w = t >> 6;
  int wm = w >> 1, wn = w & 1;
  int frow = lane & 15, kg = lane >> 4;

  f32x4 acc[4][4] = {};

  int srow = t >> 2;
  int q    = t & 3;

  for (int k0 = 0; k0 < Ktot; k0 += 32){
    __syncthreads();
    #pragma unroll
    for (int it = 0; it < 4; ++it){
      const int plane = it >> 1;
      const int row = (it & 1)*64 + srow;
      const unsigned short* gA = (plane ? pA1 : pA0) + (long)(mt+row)*lda + k0 + q*8;
      const unsigned short* gB = (plane ? pB1 : pB0) + (long)(ot+row)*ldb + k0 + q*8;
      uint4 va = *(const uint4*)gA;
      uint4 vb = *(const uint4*)gB;
      int loff = row*32 + ((q ^ (row & 3))*8);
      *(uint4*)&As[plane][loff] = va;
      *(uint4*)&Bs[plane][loff] = vb;
    }
    __syncthreads();

    bf16x8 af[2][4], bfr[2][4];
    #pragma unroll
    for (int p = 0; p < 2; ++p){
      #pragma unroll
      for (int mi = 0; mi < 4; ++mi){
        int row = wm*64 + mi*16 + frow;
        af[p][mi] = *(const bf16x8*)&As[p][row*32 + ((kg ^ (row & 3))*8)];
      }
      #pragma unroll
      for (int ni = 0; ni < 4; ++ni){
        int row = wn*64 + ni*16 + frow;
        bfr[p][ni] = *(const bf16x8*)&Bs[p][row*32 + ((kg ^ (row & 3))*8)];
      }
    }
    #pragma unroll
    for (int mi = 0; mi < 4; ++mi){
      #pragma unroll
      for (int ni = 0; ni < 4; ++ni){
        acc[mi][ni] = __builtin_amdgcn_mfma_f32_16x16x32_bf16(af[0][mi], bfr[0][ni], acc[mi][ni], 0, 0, 0);
        acc[mi][ni] = __builtin_amdgcn_mfma_f32_16x16x32_bf16(af[0][mi], bfr[1][ni], acc[mi][ni], 0, 0, 0);
        acc[mi][ni] = __builtin_amdgcn_mfma_f32_16x16x32_bf16(af[1][mi], bfr[0][ni], acc[mi][ni], 0, 0, 0);
      }
    }
  }

  if (POST == 0){
    float* ob = out + (long)b*sO;
    #pragma unroll
    for (int mi = 0; mi < 4; ++mi){
      int grow0 = mt + wm*64 + mi*16 + kg*4;
      #pragma unroll
      for (int ni = 0; ni < 4; ++ni){
        int gcol = ot + wn*64 + ni*16 + frow;
        #pragma unroll
        for (int j = 0; j < 4; ++j)
          ob[(long)(grow0+j)*ldo + gcol] = acc[mi][ni][j];
      }
    }
  } else if (POST == 1){
    const float* nb = nrm + b*NPTS;
    float* ob = out + (long)b*sO;
    bool mirror = (mt != ot);
    #pragma unroll
    for (int mi = 0; mi < 4; ++mi){
      int grow0 = mt + wm*64 + mi*16 + kg*4;
      float n0 = nb[grow0], n1 = nb[grow0+1], n2 = nb[grow0+2], n3 = nb[grow0+3];
      #pragma unroll
      for (int ni = 0; ni < 4; ++ni){
        int gcol = ot + wn*64 + ni*16 + frow;
        float nj = nb[gcol];
        float t0 = 2.f*acc[mi][ni][0] - n0 - nj;
        float t1 = 2.f*acc[mi][ni][1] - n1 - nj;
        float t2 = 2.f*acc[mi][ni][2] - n2 - nj;
        float t3 = 2.f*acc[mi][ni][3] - n3 - nj;
        ob[(long)(grow0+0)*ldo + gcol] = t0;
        ob[(long)(grow0+1)*ldo + gcol] = t1;
        ob[(long)(grow0+2)*ldo + gcol] = t2;
        ob[(long)(grow0+3)*ldo + gcol] = t3;
        if (mirror)
          *(float4*)&ob[(long)gcol*ldo + grow0] = make_float4(t0, t1, t2, t3);
      }
    }
  } else {
    #pragma unroll
    for (int ni = 0; ni < 4; ++ni){
      int o = ot + wn*64 + ni*16 + frow;
      float s = gam[o]*BNF, sh = bet[o];
      float mv = -INFINITY;
      #pragma unroll
      for (int mi = 0; mi < 4; ++mi){
        #pragma unroll
        for (int j = 0; j < 4; ++j){
          float y = acc[mi][ni][j]*s + sh;
          mv = fmaxf(mv, y >= 0.f ? y : 0.2f*y);
        }
      }
      mv = fmaxf(mv, __shfl_xor(mv, 16, 64));
      mv = fmaxf(mv, __shfl_xor(mv, 32, 64));
      if (lane < 16) atomicMaxFloat(&pool[b*NPTS + o], mv);
    }
  }
}

// -------- gather-max: bf16 hi/lo out + fused norm (Sum best^2, chained) --------
template<int O, bool NRM>
__global__ void k_gather(const float* __restrict__ UV, int ldUV,
                         const int* __restrict__ idx,
                         const float* __restrict__ gam, const float* __restrict__ bet,
                         unsigned short* __restrict__ oh, unsigned short* __restrict__ ol, int ldo,
                         float* __restrict__ nrm_out, const float* __restrict__ nrm_prev)
{
  constexpr int PPB = 256 / O;
  __shared__ float red[256];
  int t = threadIdx.x;
  int p = blockIdx.x*PPB + t/O;
  int o = t % O;
  int b = p >> 10;
  float u = UV[(long)p*ldUV + o];
  float v = UV[(long)p*ldUV + O + o];
  float base = v - u;
  float s = gam[o]*BNF, sh = bet[o];
  const int* ip = idx + p*KNN;
  const float* UVb = UV + (long)(b << 10)*ldUV;
  float best = -INFINITY;
  for (int k = 0; k < KNN; ++k){
    int j = ip[k];
    float y = (UVb[(long)j*ldUV + o] + base)*s + sh;
    best = fmaxf(best, y >= 0.f ? y : 0.2f*y);
  }
  long oo = (long)p*ldo + o;
  unsigned short h = f2bf(best);
  oh[oo] = h;
  ol[oo] = f2bf(best - bf2f(h));
  if (NRM){
    float sq = best*best;
    if (O == 64){
      #pragma unroll
      for (int off = 32; off >= 1; off >>= 1) sq += __shfl_xor(sq, off, 64);
      if ((t & 63) == 0) nrm_out[p] = sq + (nrm_prev ? nrm_prev[p] : 0.f);
    } else {
      red[t] = sq;
      __syncthreads();
      if (t < 128) red[t] += red[t+128];
      __syncthreads();
      if (t < 64){
        float a = red[t] + red[t+64];
        #pragma unroll
        for (int off = 32; off >= 1; off >>= 1) a += __shfl_xor(a, off, 64);
        if (t == 0) nrm_out[p] = a + (nrm_prev ? nrm_prev[p] : 0.f);
      }
    }
  }
}

// ---------------- FC layers: one wave per output row, all 8 batches ----------------
__global__ void k_fc1(const float* __restrict__ p1, const float* __restrict__ p2,
                      const float* __restrict__ L1, const float* __restrict__ g6,
                      const float* __restrict__ b6, float* __restrict__ f1)
{
  int t = threadIdx.x;
  int lane = t & 63;
  int o = blockIdx.x*4 + (t >> 6);
  const float* w = L1 + (long)o*2048;
  float acc[BATCH] = {};
  for (int c0 = lane*4; c0 < 2048; c0 += 256){
    float4 wv = *(const float4*)(w + c0);
    const float* fb = (c0 < 1024) ? (p1 + c0) : (p2 + c0 - 1024);
    #pragma unroll
    for (int b = 0; b < BATCH; ++b){
      float4 fv = *(const float4*)(fb + b*1024);
      acc[b] += wv.x*fv.x + wv.y*fv.y + wv.z*fv.z + wv.w*fv.w;
    }
  }
  float s = g6[o]*BNF, sh = b6[o];
  #pragma unroll
  for (int b = 0; b < BATCH; ++b){
    float a = acc[b];
    #pragma unroll
    for (int off = 32; off >= 1; off >>= 1) a += __shfl_xor(a, off, 64);
    if (lane == b) f1[b*512 + o] = leakyf(a*s + sh);
  }
}

__global__ void k_fc2(const float* __restrict__ f1, const float* __restrict__ L2,
                      const float* __restrict__ bL2, const float* __restrict__ g7,
                      const float* __restrict__ b7, float* __restrict__ f2)
{
  int t = threadIdx.x;
  int lane = t & 63;
  int o = blockIdx.x*4 + (t >> 6);
  const float* w = L2 + (long)o*512 + lane*8;
  float4 w0 = *(const float4*)w;
  float4 w1 = *(const float4*)(w + 4);
  float s = g7[o]*BNF, sh = bL2[o]*g7[o]*BNF + b7[o];
  #pragma unroll
  for (int b = 0; b < BATCH; ++b){
    const float* fb = f1 + b*512 + lane*8;
    float4 f0 = *(const float4*)fb;
    float f1v0 = fb[4], f1v1 = fb[5], f1v2 = fb[6], f1v3 = fb[7];
    float a = w0.x*f0.x + w0.y*f0.y + w0.z*f0.z + w0.w*f0.w
            + w1.x*f1v0 + w1.y*f1v1 + w1.z*f1v2 + w1.w*f1v3;
    #pragma unroll
    for (int off = 32; off >= 1; off >>= 1) a += __shfl_xor(a, off, 64);
    if (lane == b) f2[b*256 + o] = leakyf(a*s + sh);
  }
}

__global__ void k_fc3(const float* __restrict__ f2, const float* __restrict__ L3,
                      const float* __restrict__ bL3, float* __restrict__ out)
{
  int lane = threadIdx.x;
  int o = blockIdx.x;
  float4 wv = *(const float4*)(L3 + (long)o*256 + lane*4);
  float bias = bL3[o];
  #pragma unroll
  for (int b = 0; b < BATCH; ++b){
    float4 fv = *(const float4*)(f2 + b*256 + lane*4);
    float a = wv.x*fv.x + wv.y*fv.y + wv.z*fv.z + wv.w*fv.w;
    #pragma unroll
    for (int off = 32; off >= 1; off >>= 1) a += __shfl_xor(a, off, 64);
    if (lane == b) out[b*40 + o] = a + bias;
  }
}

extern "C" void kernel_launch(void* const* d_in, const int* in_sizes, int n_in,
                              void* d_out, int out_size, void* d_ws, size_t ws_size,
                              hipStream_t stream) {
  const float* x   = (const float*)d_in[0];
  const float* W1  = (const float*)d_in[1];
  const float* g1  = (const float*)d_in[2];
  const float* b1  = (const float*)d_in[3];
  const float* W2  = (const float*)d_in[4];
  const float* g2  = (const float*)d_in[5];
  const float* b2  = (const float*)d_in[6];
  const float* W2m = (const float*)d_in[7];
  const float* g2m = (const float*)d_in[8];
  const float* b2m = (const float*)d_in[9];
  const float* W3  = (const float*)d_in[10];
  const float* g3  = (const float*)d_in[11];
  const float* b3  = (const float*)d_in[12];
  const float* W4  = (const float*)d_in[13];
  const float* g4  = (const float*)d_in[14];
  const float* b4  = (const float*)d_in[15];
  const float* W5  = (const float*)d_in[16];
  const float* g5  = (const float*)d_in[17];
  const float* b5  = (const float*)d_in[18];
  const float* L1  = (const float*)d_in[19];
  const float* g6  = (const float*)d_in[20];
  const float* b6  = (const float*)d_in[21];
  const float* L2  = (const float*)d_in[22];
  const float* bL2 = (const float*)d_in[23];
  const float* g7  = (const float*)d_in[24];
  const float* b7  = (const float*)d_in[25];
  const float* L3  = (const float*)d_in[26];
  const float* bL3 = (const float*)d_in[27];

  float* ws = (float*)d_ws;
  size_t off = 0;
  auto alloc = [&](size_t n)->float*{ float* p = ws + off; off += (n + 255) & ~(size_t)255; return p; };
  float* xt   = alloc((size_t)BATCH*NPTS*3);
  float* nrmA = alloc((size_t)BATCH*NPTS);
  float* nrmB = alloc((size_t)BATCH*NPTS);
  float* nrmC = alloc((size_t)BATCH*NPTS);
  float* D    = alloc((size_t)BATCH*NPTS*NPTS);
  int*   idx  = (int*)alloc((size_t)BATCH*NPTS*KNN);
  float* UVbuf= alloc((size_t)BATCH*NPTS*512);
  float* p1   = alloc((size_t)BATCH*1024);
  float* p2   = alloc((size_t)BATCH*1024);
  float* f1   = alloc((size_t)BATCH*512);
  float* f2   = alloc((size_t)BATCH*256);

  auto ualloc = [&](size_t n_us)->unsigned short*{ return (unsigned short*)alloc((n_us + 1) / 2); };
  unsigned short* fh  = ualloc((size_t)BATCH*NPTS*128);
  unsigned short* fl  = ualloc((size_t)BATCH*NPTS*128);
  unsigned short* ch  = ualloc((size_t)BATCH*NPTS*512);
  unsigned short* cl  = ualloc((size_t)BATCH*NPTS*512);
  unsigned short* w2h = ualloc(128*64);
  unsigned short* w2l = ualloc(128*64);
  unsigned short* w3h = ualloc(512*128);
  unsigned short* w3l = ualloc(512*128);
  unsigned short* w4h = ualloc(512*256);
  unsigned short* w4l = ualloc(512*256);
  unsigned short* wmh = ualloc(1024*128);
  unsigned short* wml = ualloc(1024*128);
  unsigned short* w5h = ualloc(1024*512);
  unsigned short* w5l = ualloc(1024*512);

  if (off * sizeof(float) > ws_size) return;  // insufficient workspace -> fail loudly

  const long sF = (long)NPTS*128;
  const long sC = (long)NPTS*512;
  const long sD = (long)NPTS*NPTS;

  // ---- one-shot prep: weights pack+split, pool init, x transpose ----
  k_prep<<<880, 256, 0, stream>>>(x, W2, W3, W4, W2m, W5,
                                  w2h, w2l, w3h, w3l, w4h, w4l, wmh, wml, w5h, w5l,
                                  p1, p2, xt);

  // ---- EdgeConv 1 (C=3 -> 64), distance fused into topk ----
  k_uv1<<<BATCH*NPTS, 128, 0, stream>>>(xt, W1, UVbuf);
  k_topk1<<<BATCH*NPTS/4, 256, 0, stream>>>(xt, idx);
  k_gather<64,true><<<BATCH*NPTS/4, 256, 0, stream>>>(UVbuf, 128, idx, g1, b1, fh, fl, 128, nrmA, nullptr);

  dim3 gD(36, 1, BATCH);
  // ---- EdgeConv 2 (C=64 -> 64) ----
  k_mgemm<1><<<gD, 256, 0, stream>>>(fh, fl, 128, sF, fh, fl, 128, sF, D, NPTS, sD, 64, nrmA, nullptr, nullptr, nullptr);
  k_topkD<<<BATCH*NPTS/4, 256, 0, stream>>>(D, idx);
  dim3 gUV2(8, 1, BATCH);
  k_mgemm<0><<<gUV2, 256, 0, stream>>>(fh, fl, 128, sF, w2h, w2l, 64, 0, UVbuf, 128, sF, 64, nullptr, nullptr, nullptr, nullptr);
  k_gather<64,true><<<BATCH*NPTS/4, 256, 0, stream>>>(UVbuf, 128, idx, g2, b2, fh + 64, fl + 64, 128, nrmB, nrmA);

  // ---- EdgeConv 3 (folded: C=128 -> 256) ----
  k_mgemm<1><<<gD, 256, 0, stream>>>(fh, fl, 128, sF, fh, fl, 128, sF, D, NPTS, sD, 128, nrmB, nullptr, nullptr, nullptr);
  k_topkD<<<BATCH*NPTS/4, 256, 0, stream>>>(D, idx);
  dim3 gUV3(8, 4, BATCH);
  k_mgemm<0><<<gUV3, 256, 0, stream>>>(fh, fl, 128, sF, w3h, w3l, 128, 0, UVbuf, 512, sC, 128, nullptr, nullptr, nullptr, nullptr);
  k_gather<256,true><<<BATCH*NPTS, 256, 0, stream>>>(UVbuf, 512, idx, g3, b3, ch, cl, 512, nrmC, nullptr);

  // ---- EdgeConv 4 (C=256 -> 256) ----
  k_mgemm<1><<<gD, 256, 0, stream>>>(ch, cl, 512, sC, ch, cl, 512, sC, D, NPTS, sD, 256, nrmC, nullptr, nullptr, nullptr);
  k_topkD<<<BATCH*NPTS/4, 256, 0, stream>>>(D, idx);
  k_mgemm<0><<<gUV3, 256, 0, stream>>>(ch, cl, 512, sC, w4h, w4l, 256, 0, UVbuf, 512, sC, 256, nullptr, nullptr, nullptr, nullptr);
  k_gather<256,false><<<BATCH*NPTS, 256, 0, stream>>>(UVbuf, 512, idx, g4, b4, ch + 256, cl + 256, 512, nullptr, nullptr);

  // ---- fused pool projections ----
  dim3 gP(8, 8, BATCH);
  k_mgemm<2><<<gP, 256, 0, stream>>>(fh, fl, 128, sF, wmh, wml, 128, 0, nullptr, 0, 0, 128, nullptr, g2m, b2m, p1);
  k_mgemm<2><<<gP, 256, 0, stream>>>(ch, cl, 512, sC, w5h, w5l, 512, 0, nullptr, 0, 0, 512, nullptr, g5, b5, p2);

  // ---- FC head ----
  k_fc1<<<128, 256, 0, stream>>>(p1, p2, L1, g6, b6, f1);
  k_fc2<<<64, 256, 0, stream>>>(f1, L2, bL2, g7, b7, f2);
  k_fc3<<<40, 64, 0, stream>>>(f2, L3, bL3, (float*)d_out);
}

// Round 6
// 248.807 us; speedup vs baseline: 2.9259x; 1.2446x over previous
//
#include <hip/hip_runtime.h>
#include <math.h>

#define BATCH 8
#define NPTS  1024
#define KNN   20
#define BNF   0.99999500003749937f  // 1/sqrt(1+1e-5)

typedef short bf16x8 __attribute__((ext_vector_type(8)));
typedef float f32x4  __attribute__((ext_vector_type(4)));

__device__ __forceinline__ float leakyf(float x){ return x >= 0.f ? x : 0.2f*x; }

__device__ __forceinline__ void atomicMaxFloat(float* addr, float val){
  if (val >= 0.f) atomicMax((int*)addr, __float_as_int(val));
  else            atomicMin((unsigned int*)addr, __float_as_uint(val));
}

__device__ __forceinline__ unsigned short f2bf(float x){
  unsigned u = __float_as_uint(x);
  unsigned r = (u + 0x7FFFu + ((u >> 16) & 1u)) >> 16;   // RNE (no NaN/inf in data)
  return (unsigned short)r;
}
__device__ __forceinline__ float bf2f(unsigned short h){
  return __uint_as_float(((unsigned)h) << 16);
}

// monotone f32 -> u32 key (exact order-preserving)
__device__ __forceinline__ unsigned ordkey(float x){
  unsigned u = __float_as_uint(x);
  unsigned mask = (unsigned)(((int)u) >> 31) | 0x80000000u;
  return u ^ mask;
}

// =====================================================================
// k_prep: weight pack+split, pool init, x transpose, EC1 U/V projection.
// 4-elem units: S1 2048 | S2 16384 | S3 32768 | S4 32768 | S5 131072
//               S6 4096 | S7 6144  -> 225280
// S8 (1-elem units): UV1 = 1048576.  total threads = 1273856 = 4976*256
// =====================================================================
__device__ __forceinline__ void split4store(float v0, float v1, float v2, float v3,
                                            unsigned short* hi, unsigned short* lo, long off){
  unsigned short h0=f2bf(v0), h1=f2bf(v1), h2=f2bf(v2), h3=f2bf(v3);
  *(ushort4*)(hi+off) = make_ushort4(h0,h1,h2,h3);
  *(ushort4*)(lo+off) = make_ushort4(f2bf(v0-bf2f(h0)), f2bf(v1-bf2f(h1)),
                                     f2bf(v2-bf2f(h2)), f2bf(v3-bf2f(h3)));
}

__global__ __launch_bounds__(256) void k_prep(
    const float* __restrict__ x,  const float* __restrict__ W1,
    const float* __restrict__ W2, const float* __restrict__ W3,
    const float* __restrict__ W4, const float* __restrict__ W2m,
    const float* __restrict__ W5,
    unsigned short* __restrict__ w2h, unsigned short* __restrict__ w2l,
    unsigned short* __restrict__ w3h, unsigned short* __restrict__ w3l,
    unsigned short* __restrict__ w4h, unsigned short* __restrict__ w4l,
    unsigned short* __restrict__ wmh, unsigned short* __restrict__ wml,
    unsigned short* __restrict__ w5h, unsigned short* __restrict__ w5l,
    float* __restrict__ p1, float* __restrict__ p2, float* __restrict__ xt,
    float* __restrict__ UV)
{
  int u = blockIdx.x*256 + threadIdx.x;
  if (u < 2048){                                   // S1: W2 pack+split
    int o = u >> 4, c = (u & 15) * 4;
    const float* s = (o < 64) ? (W2 + o*128 + c) : (W2 + (o-64)*128 + 64 + c);
    float4 v = *(const float4*)s;
    split4store(v.x,v.y,v.z,v.w, w2h,w2l, (long)o*64 + c);
    return;
  }
  u -= 2048;
  if (u < 16384){                                  // S2: W3 fold+split
    int o = u >> 5, c = (u & 31) * 4;
    const float* s = (o < 256) ? (W3 + o*512 + c) : (W3 + (o-256)*512 + 256 + c);
    float4 a = *(const float4*)s;
    float4 b = *(const float4*)(s + 128);
    split4store(a.x+b.x, a.y+b.y, a.z+b.z, a.w+b.w, w3h,w3l, (long)o*128 + c);
    return;
  }
  u -= 16384;
  if (u < 32768){                                  // S3: W4 pack+split
    int o = u >> 6, c = (u & 63) * 4;
    const float* s = (o < 256) ? (W4 + o*512 + c) : (W4 + (o-256)*512 + 256 + c);
    float4 v = *(const float4*)s;
    split4store(v.x,v.y,v.z,v.w, w4h,w4l, (long)o*256 + c);
    return;
  }
  u -= 32768;
  if (u < 32768){                                  // S4: W2m split
    int r = u >> 5, c = (u & 31) * 4;
    float4 v = *(const float4*)(W2m + (long)r*128 + c);
    split4store(v.x,v.y,v.z,v.w, wmh,wml, (long)r*128 + c);
    return;
  }
  u -= 32768;
  if (u < 131072){                                 // S5: W5 split
    int r = u >> 7, c = (u & 127) * 4;
    float4 v = *(const float4*)(W5 + (long)r*512 + c);
    split4store(v.x,v.y,v.z,v.w, w5h,w5l, (long)r*512 + c);
    return;
  }
  u -= 131072;
  if (u < 4096){                                   // S6: pool init
    float4 ninf = make_float4(-INFINITY,-INFINITY,-INFINITY,-INFINITY);
    if (u < 2048) *(float4*)(p1 + u*4) = ninf;
    else          *(float4*)(p2 + (u-2048)*4) = ninf;
    return;
  }
  u -= 4096;
  if (u < 6144){                                   // S7: transpose x -> xt
    int b = u / 768, rem = u % 768;
    int c = rem >> 8, n0 = (rem & 255) * 4;
    float4 v = *(const float4*)(x + ((long)b*3 + c)*NPTS + n0);
    float* o = xt + (long)b*NPTS*3;
    o[(n0+0)*3 + c] = v.x; o[(n0+1)*3 + c] = v.y;
    o[(n0+2)*3 + c] = v.z; o[(n0+3)*3 + c] = v.w;
    return;
  }
  u -= 6144;
  {                                                // S8: EC1 U/V from x directly
    int p = u >> 7, o = u & 127;
    int b = p >> 10, n = p & 1023;
    const float* xb = x + (long)b*3*NPTS + n;
    float x0 = xb[0], x1 = xb[NPTS], x2 = xb[2*NPTS];
    const float* w = (o < 64) ? (W1 + o*6) : (W1 + (o-64)*6 + 3);
    UV[(long)p*128 + o] = w[0]*x0 + w[1]*x1 + w[2]*x2;
  }
}

// ================= top-20 selection (exact: value desc, index asc) =================
__device__ __forceinline__ unsigned wave_max_u32(unsigned x){
  unsigned t;
  t = (unsigned)__builtin_amdgcn_update_dpp((int)x, (int)x, 0x111, 0xf, 0xf, false); x = x > t ? x : t;
  t = (unsigned)__builtin_amdgcn_update_dpp((int)x, (int)x, 0x112, 0xf, 0xf, false); x = x > t ? x : t;
  t = (unsigned)__builtin_amdgcn_update_dpp((int)x, (int)x, 0x114, 0xf, 0xf, false); x = x > t ? x : t;
  t = (unsigned)__builtin_amdgcn_update_dpp((int)x, (int)x, 0x118, 0xf, 0xf, false); x = x > t ? x : t;
  t = (unsigned)__builtin_amdgcn_update_dpp((int)x, (int)x, 0x142, 0xa, 0xf, false); x = x > t ? x : t;
  t = (unsigned)__builtin_amdgcn_update_dpp((int)x, (int)x, 0x143, 0xc, 0xf, false); x = x > t ? x : t;
  return (unsigned)__builtin_amdgcn_readlane((int)x, 63);
}

__device__ __forceinline__ void topk_select(unsigned long long* sk,
                                            unsigned long long* lds,
                                            int* out, int lane)
{
  #define CE(a,b) { unsigned long long ka=sk[a], kb=sk[b]; bool sw=ka<kb; sk[a]=sw?kb:ka; sk[b]=sw?ka:kb; }
  CE(0,1) CE(2,3) CE(4,5) CE(6,7) CE(8,9) CE(10,11) CE(12,13) CE(14,15)
  CE(0,2) CE(1,3) CE(4,6) CE(5,7) CE(8,10) CE(9,11) CE(12,14) CE(13,15)
  CE(1,2) CE(5,6) CE(9,10) CE(13,14)
  CE(0,4) CE(1,5) CE(2,6) CE(3,7) CE(8,12) CE(9,13) CE(10,14) CE(11,15)
  CE(2,4) CE(3,5) CE(10,12) CE(11,13)
  CE(1,2) CE(3,4) CE(5,6) CE(9,10) CE(11,12) CE(13,14)
  CE(0,8) CE(1,9) CE(2,10) CE(3,11) CE(4,12) CE(5,13) CE(6,14) CE(7,15)
  CE(4,8) CE(5,9) CE(6,10) CE(7,11)
  CE(2,4) CE(3,5) CE(6,8) CE(7,9) CE(10,12) CE(11,13)
  CE(1,2) CE(3,4) CE(5,6) CE(7,8) CE(9,10) CE(11,12) CE(13,14)
  #undef CE

  #pragma unroll
  for (int m = 0; m < 16; ++m){
    unsigned key = (unsigned)(sk[m] >> 4);
    unsigned slot = 15u - ((unsigned)sk[m] & 15u);
    lds[m*64 + lane] = ((unsigned long long)slot << 32) | (unsigned long long)key;
  }
  lds[16*64 + lane] = 0ull;
  lds[17*64 + lane] = 0ull;

  unsigned hk = (unsigned)(sk[0] >> 4); int hs = 15 - (int)((unsigned)sk[0] & 15u);
  unsigned nk = (unsigned)(sk[1] >> 4); int ns = 15 - (int)((unsigned)sk[1] & 15u);
  int p = 2;

  #pragma unroll
  for (int it = 0; it < KNN; ++it){
    unsigned g = wave_max_u32(hk);
    unsigned long long mask = __ballot(hk == g);
    int wl = __ffsll((long long)mask) - 1;
    int ws = __builtin_amdgcn_readlane(hs, wl);
    if (lane == 0) out[it] = wl*16 + ws;
    bool win = ((int)lane == wl);
    hk = win ? nk : hk;
    hs = win ? ns : hs;
    if (win){
      unsigned long long e = lds[p*64 + lane];
      nk = (unsigned)e; ns = (int)(e >> 32);
      p++;
    }
  }
}

// ============ fused topk + gather(+bf16 split, + chained norm) ============
// 4 waves/block, wave w owns row blockIdx*4+w for BOTH selection and gather.
template<bool EC1, int O, bool NRM>
__global__ __launch_bounds__(256) void k_topkg(
    const float* __restrict__ src,          // EC1 ? xt : D
    const float* __restrict__ UV, int ldUV,
    const float* __restrict__ gam, const float* __restrict__ bet,
    unsigned short* __restrict__ oh, unsigned short* __restrict__ ol, int ldo,
    float* __restrict__ nrm_out, const float* __restrict__ nrm_prev)
{
  __shared__ unsigned long long lds[4][18*64];
  __shared__ int idxs[4][KNN];
  int t = threadIdx.x, lane = t & 63, w = t >> 6;
  int row = blockIdx.x*4 + w;
  unsigned long long sk[16];
  if (EC1){
    int b = row >> 10, i0 = row & 1023;
    const float* base = src + (long)b*NPTS*3;
    float cx = base[i0*3], cy = base[i0*3+1], cz = base[i0*3+2];
    float pts[48];
    #pragma unroll
    for (int q = 0; q < 12; ++q)
      *(float4*)&pts[q*4] = *(const float4*)&base[lane*48 + q*4];
    #pragma unroll
    for (int m = 0; m < 16; ++m){
      float dx = pts[m*3]-cx, dy = pts[m*3+1]-cy, dz = pts[m*3+2]-cz;
      float d = -(dx*dx + dy*dy + dz*dz);
      sk[m] = ((unsigned long long)ordkey(d) << 4) | (unsigned long long)(15 - m);
    }
  } else {
    const float* Dr = src + (long)row*NPTS + lane*16;
    float v[16];
    #pragma unroll
    for (int q = 0; q < 4; ++q)
      *(float4*)&v[q*4] = *(const float4*)&Dr[q*4];
    #pragma unroll
    for (int m = 0; m < 16; ++m)
      sk[m] = ((unsigned long long)ordkey(v[m]) << 4) | (unsigned long long)(15 - m);
  }
  topk_select(sk, lds[w], idxs[w], lane);
  __syncthreads();

  // ---- gather phase: wave w -> point row ----
  int p = row;
  int b = p >> 10;
  const float* UVb = UV + (long)(b << 10)*ldUV;
  const float* UVp = UV + (long)p*ldUV;
  float sqsum = 0.f;
  #pragma unroll
  for (int jj = 0; jj < O/64; ++jj){
    int o = lane + jj*64;
    float uu = UVp[o];
    float vv = UVp[O + o];
    float base = vv - uu;
    float s = gam[o]*BNF, sh = bet[o];
    float best = -INFINITY;
    for (int k = 0; k < KNN; ++k){
      int j = idxs[w][k];
      float y = (UVb[(long)j*ldUV + o] + base)*s + sh;
      best = fmaxf(best, leakyf(y));
    }
    long oo = (long)p*ldo + o;
    unsigned short h = f2bf(best);
    oh[oo] = h;
    ol[oo] = f2bf(best - bf2f(h));
    sqsum += best*best;
  }
  if (NRM){
    #pragma unroll
    for (int off = 32; off >= 1; off >>= 1) sqsum += __shfl_xor(sqsum, off, 64);
    if (lane == 0) nrm_out[p] = sqsum + (nrm_prev ? nrm_prev[p] : 0.f);
  }
}

// =====================================================================
// shared split-bf16 MFMA tile core: acc += A(128 rows @mt) * B(128 rows @ot)^T
// =====================================================================
__device__ __forceinline__ void gemm_tile(
    const unsigned short* __restrict__ pA0, const unsigned short* __restrict__ pA1, int lda,
    const unsigned short* __restrict__ pB0, const unsigned short* __restrict__ pB1, int ldb,
    int mt, int ot, int Ktot,
    unsigned short As[2][128*32], unsigned short Bs[2][128*32],
    f32x4 acc[4][4], int t)
{
  int lane = t & 63, w = t >> 6;
  int wm = w >> 1, wn = w & 1;
  int frow = lane & 15, kg = lane >> 4;
  int srow = t >> 2, q = t & 3;

  for (int k0 = 0; k0 < Ktot; k0 += 32){
    __syncthreads();
    #pragma unroll
    for (int it = 0; it < 4; ++it){
      const int plane = it >> 1;
      const int row = (it & 1)*64 + srow;
      const unsigned short* gA = (plane ? pA1 : pA0) + (long)(mt+row)*lda + k0 + q*8;
      const unsigned short* gB = (plane ? pB1 : pB0) + (long)(ot+row)*ldb + k0 + q*8;
      uint4 va = *(const uint4*)gA;
      uint4 vb = *(const uint4*)gB;
      int loff = row*32 + ((q ^ (row & 3))*8);
      *(uint4*)&As[plane][loff] = va;
      *(uint4*)&Bs[plane][loff] = vb;
    }
    __syncthreads();

    bf16x8 af[2][4], bfr[2][4];
    #pragma unroll
    for (int pl = 0; pl < 2; ++pl){
      #pragma unroll
      for (int mi = 0; mi < 4; ++mi){
        int row = wm*64 + mi*16 + frow;
        af[pl][mi] = *(const bf16x8*)&As[pl][row*32 + ((kg ^ (row & 3))*8)];
      }
      #pragma unroll
      for (int ni = 0; ni < 4; ++ni){
        int row = wn*64 + ni*16 + frow;
        bfr[pl][ni] = *(const bf16x8*)&Bs[pl][row*32 + ((kg ^ (row & 3))*8)];
      }
    }
    #pragma unroll
    for (int mi = 0; mi < 4; ++mi){
      #pragma unroll
      for (int ni = 0; ni < 4; ++ni){
        acc[mi][ni] = __builtin_amdgcn_mfma_f32_16x16x32_bf16(af[0][mi], bfr[0][ni], acc[mi][ni], 0, 0, 0);
        acc[mi][ni] = __builtin_amdgcn_mfma_f32_16x16x32_bf16(af[0][mi], bfr[1][ni], acc[mi][ni], 0, 0, 0);
        acc[mi][ni] = __builtin_amdgcn_mfma_f32_16x16x32_bf16(af[1][mi], bfr[0][ni], acc[mi][ni], 0, 0, 0);
      }
    }
  }
}

// ============ combined distance (triangular+mirror) + UV projection ============
__global__ __launch_bounds__(256) void k_mgc(
    const unsigned short* __restrict__ Fh, const unsigned short* __restrict__ Fl,
    int ldf, long sFt,
    const unsigned short* __restrict__ Wh, const unsigned short* __restrict__ Wl,
    float* __restrict__ D, const float* __restrict__ nrm,
    float* __restrict__ UV, int ldUV, long sUV,
    int Ktot, int nDist)
{
  __shared__ unsigned short As[2][128*32];
  __shared__ unsigned short Bs[2][128*32];
  int b = blockIdx.z;
  int t = threadIdx.x;
  int lane = t & 63, w = t >> 6;
  int wm = w >> 1, wn = w & 1;
  int frow = lane & 15, kg = lane >> 4;
  f32x4 acc[4][4] = {};
  const unsigned short* pA0 = Fh + (long)b*sFt;
  const unsigned short* pA1 = Fl + (long)b*sFt;

  if ((int)blockIdx.x < nDist){
    int u = blockIdx.x, r = 0;
    while (u >= 8 - r){ u -= 8 - r; ++r; }
    int mt = r*128, ot = (r + u)*128;
    gemm_tile(pA0, pA1, ldf, pA0, pA1, ldf, mt, ot, Ktot, As, Bs, acc, t);
    const float* nb = nrm + b*NPTS;
    float* ob = D + (long)b*NPTS*NPTS;
    bool mirror = (mt != ot);
    #pragma unroll
    for (int mi = 0; mi < 4; ++mi){
      int grow0 = mt + wm*64 + mi*16 + kg*4;
      float n0 = nb[grow0], n1 = nb[grow0+1], n2 = nb[grow0+2], n3 = nb[grow0+3];
      #pragma unroll
      for (int ni = 0; ni < 4; ++ni){
        int gcol = ot + wn*64 + ni*16 + frow;
        float nj = nb[gcol];
        float t0 = 2.f*acc[mi][ni][0] - n0 - nj;
        float t1 = 2.f*acc[mi][ni][1] - n1 - nj;
        float t2 = 2.f*acc[mi][ni][2] - n2 - nj;
        float t3 = 2.f*acc[mi][ni][3] - n3 - nj;
        ob[(long)(grow0+0)*NPTS + gcol] = t0;
        ob[(long)(grow0+1)*NPTS + gcol] = t1;
        ob[(long)(grow0+2)*NPTS + gcol] = t2;
        ob[(long)(grow0+3)*NPTS + gcol] = t3;
        if (mirror)
          *(float4*)&ob[(long)gcol*NPTS + grow0] = make_float4(t0, t1, t2, t3);
      }
    }
  } else {
    int v = blockIdx.x - nDist;
    int mt = (v & 7)*128, ot = (v >> 3)*128;
    gemm_tile(pA0, pA1, ldf, Wh, Wl, Ktot, mt, ot, Ktot, As, Bs, acc, t);
    float* ob = UV + (long)b*sUV;
    #pragma unroll
    for (int mi = 0; mi < 4; ++mi){
      int grow0 = mt + wm*64 + mi*16 + kg*4;
      #pragma unroll
      for (int ni = 0; ni < 4; ++ni){
        int gcol = ot + wn*64 + ni*16 + frow;
        #pragma unroll
        for (int j = 0; j < 4; ++j)
          ob[(long)(grow0+j)*ldUV + gcol] = acc[mi][ni][j];
      }
    }
  }
}

// ============ combined pool projections (bn+leaky+max over points) ============
__global__ __launch_bounds__(256) void k_poolc(
    const unsigned short* __restrict__ A1h, const unsigned short* __restrict__ A1l,
    const unsigned short* __restrict__ B1h, const unsigned short* __restrict__ B1l,
    const float* __restrict__ gA, const float* __restrict__ bA, float* __restrict__ poolA,
    const unsigned short* __restrict__ A2h, const unsigned short* __restrict__ A2l,
    const unsigned short* __restrict__ B2h, const unsigned short* __restrict__ B2l,
    const float* __restrict__ gB, const float* __restrict__ bB, float* __restrict__ poolB)
{
  __shared__ unsigned short As[2][128*32];
  __shared__ unsigned short Bs[2][128*32];
  int b = blockIdx.z;
  int t = threadIdx.x;
  int lane = t & 63, w = t >> 6;
  int wn = w & 1;
  int frow = lane & 15;
  bool second = (int)blockIdx.x >= 64;
  int v = blockIdx.x & 63;
  int mt = (v & 7)*128, ot = (v >> 3)*128;
  int K = second ? 512 : 128;
  const unsigned short* pA0 = (second ? A2h : A1h) + (long)b*NPTS*K;
  const unsigned short* pA1 = (second ? A2l : A1l) + (long)b*NPTS*K;
  const unsigned short* pB0 = second ? B2h : B1h;
  const unsigned short* pB1 = second ? B2l : B1l;
  const float* gam = second ? gB : gA;
  const float* bet = second ? bB : bA;
  float* pool = second ? poolB : poolA;

  f32x4 acc[4][4] = {};
  gemm_tile(pA0, pA1, K, pB0, pB1, K, mt, ot, K, As, Bs, acc, t);

  #pragma unroll
  for (int ni = 0; ni < 4; ++ni){
    int o = ot + wn*64 + ni*16 + frow;
    float s = gam[o]*BNF, sh = bet[o];
    float mv = -INFINITY;
    #pragma unroll
    for (int mi = 0; mi < 4; ++mi){
      #pragma unroll
      for (int j = 0; j < 4; ++j){
        float y = acc[mi][ni][j]*s + sh;
        mv = fmaxf(mv, y >= 0.f ? y : 0.2f*y);
      }
    }
    mv = fmaxf(mv, __shfl_xor(mv, 16, 64));
    mv = fmaxf(mv, __shfl_xor(mv, 32, 64));
    if (lane < 16) atomicMaxFloat(&pool[b*NPTS + o], mv);
  }
}

// ---------------- FC layers: one wave per output row, all 8 batches ----------------
__global__ void k_fc1(const float* __restrict__ p1, const float* __restrict__ p2,
                      const float* __restrict__ L1, const float* __restrict__ g6,
                      const float* __restrict__ b6, float* __restrict__ f1)
{
  int t = threadIdx.x;
  int lane = t & 63;
  int o = blockIdx.x*4 + (t >> 6);
  const float* w = L1 + (long)o*2048;
  float acc[BATCH] = {};
  for (int c0 = lane*4; c0 < 2048; c0 += 256){
    float4 wv = *(const float4*)(w + c0);
    const float* fb = (c0 < 1024) ? (p1 + c0) : (p2 + c0 - 1024);
    #pragma unroll
    for (int b = 0; b < BATCH; ++b){
      float4 fv = *(const float4*)(fb + b*1024);
      acc[b] += wv.x*fv.x + wv.y*fv.y + wv.z*fv.z + wv.w*fv.w;
    }
  }
  float s = g6[o]*BNF, sh = b6[o];
  #pragma unroll
  for (int b = 0; b < BATCH; ++b){
    float a = acc[b];
    #pragma unroll
    for (int off = 32; off >= 1; off >>= 1) a += __shfl_xor(a, off, 64);
    if (lane == b) f1[b*512 + o] = leakyf(a*s + sh);
  }
}

__global__ void k_fc2(const float* __restrict__ f1, const float* __restrict__ L2,
                      const float* __restrict__ bL2, const float* __restrict__ g7,
                      const float* __restrict__ b7, float* __restrict__ f2)
{
  int t = threadIdx.x;
  int lane = t & 63;
  int o = blockIdx.x*4 + (t >> 6);
  const float* w = L2 + (long)o*512 + lane*8;
  float4 w0 = *(const float4*)w;
  float4 w1 = *(const float4*)(w + 4);
  float s = g7[o]*BNF, sh = bL2[o]*g7[o]*BNF + b7[o];
  #pragma unroll
  for (int b = 0; b < BATCH; ++b){
    const float* fb = f1 + b*512 + lane*8;
    float4 f0 = *(const float4*)fb;
    float f1v0 = fb[4], f1v1 = fb[5], f1v2 = fb[6], f1v3 = fb[7];
    float a = w0.x*f0.x + w0.y*f0.y + w0.z*f0.z + w0.w*f0.w
            + w1.x*f1v0 + w1.y*f1v1 + w1.z*f1v2 + w1.w*f1v3;
    #pragma unroll
    for (int off = 32; off >= 1; off >>= 1) a += __shfl_xor(a, off, 64);
    if (lane == b) f2[b*256 + o] = leakyf(a*s + sh);
  }
}

__global__ void k_fc3(const float* __restrict__ f2, const float* __restrict__ L3,
                      const float* __restrict__ bL3, float* __restrict__ out)
{
  int lane = threadIdx.x;
  int o = blockIdx.x;
  float4 wv = *(const float4*)(L3 + (long)o*256 + lane*4);
  float bias = bL3[o];
  #pragma unroll
  for (int b = 0; b < BATCH; ++b){
    float4 fv = *(const float4*)(f2 + b*256 + lane*4);
    float a = wv.x*fv.x + wv.y*fv.y + wv.z*fv.z + wv.w*fv.w;
    #pragma unroll
    for (int off = 32; off >= 1; off >>= 1) a += __shfl_xor(a, off, 64);
    if (lane == b) out[b*40 + o] = a + bias;
  }
}

extern "C" void kernel_launch(void* const* d_in, const int* in_sizes, int n_in,
                              void* d_out, int out_size, void* d_ws, size_t ws_size,
                              hipStream_t stream) {
  const float* x   = (const float*)d_in[0];
  const float* W1  = (const float*)d_in[1];
  const float* g1  = (const float*)d_in[2];
  const float* b1  = (const float*)d_in[3];
  const float* W2  = (const float*)d_in[4];
  const float* g2  = (const float*)d_in[5];
  const float* b2  = (const float*)d_in[6];
  const float* W2m = (const float*)d_in[7];
  const float* g2m = (const float*)d_in[8];
  const float* b2m = (const float*)d_in[9];
  const float* W3  = (const float*)d_in[10];
  const float* g3  = (const float*)d_in[11];
  const float* b3  = (const float*)d_in[12];
  const float* W4  = (const float*)d_in[13];
  const float* g4  = (const float*)d_in[14];
  const float* b4  = (const float*)d_in[15];
  const float* W5  = (const float*)d_in[16];
  const float* g5  = (const float*)d_in[17];
  const float* b5  = (const float*)d_in[18];
  const float* L1  = (const float*)d_in[19];
  const float* g6  = (const float*)d_in[20];
  const float* b6  = (const float*)d_in[21];
  const float* L2  = (const float*)d_in[22];
  const float* bL2 = (const float*)d_in[23];
  const float* g7  = (const float*)d_in[24];
  const float* b7  = (const float*)d_in[25];
  const float* L3  = (const float*)d_in[26];
  const float* bL3 = (const float*)d_in[27];

  float* ws = (float*)d_ws;
  size_t off = 0;
  auto alloc = [&](size_t n)->float*{ float* p = ws + off; off += (n + 255) & ~(size_t)255; return p; };
  float* xt   = alloc((size_t)BATCH*NPTS*3);
  float* nrmA = alloc((size_t)BATCH*NPTS);
  float* nrmB = alloc((size_t)BATCH*NPTS);
  float* nrmC = alloc((size_t)BATCH*NPTS);
  float* D    = alloc((size_t)BATCH*NPTS*NPTS);
  float* UVbuf= alloc((size_t)BATCH*NPTS*512);
  float* p1   = alloc((size_t)BATCH*1024);
  float* p2   = alloc((size_t)BATCH*1024);
  float* f1   = alloc((size_t)BATCH*512);
  float* f2   = alloc((size_t)BATCH*256);

  auto ualloc = [&](size_t n_us)->unsigned short*{ return (unsigned short*)alloc((n_us + 1) / 2); };
  unsigned short* fh  = ualloc((size_t)BATCH*NPTS*128);
  unsigned short* fl  = ualloc((size_t)BATCH*NPTS*128);
  unsigned short* ch  = ualloc((size_t)BATCH*NPTS*512);
  unsigned short* cl  = ualloc((size_t)BATCH*NPTS*512);
  unsigned short* w2h = ualloc(128*64);
  unsigned short* w2l = ualloc(128*64);
  unsigned short* w3h = ualloc(512*128);
  unsigned short* w3l = ualloc(512*128);
  unsigned short* w4h = ualloc(512*256);
  unsigned short* w4l = ualloc(512*256);
  unsigned short* wmh = ualloc(1024*128);
  unsigned short* wml = ualloc(1024*128);
  unsigned short* w5h = ualloc(1024*512);
  unsigned short* w5l = ualloc(1024*512);

  if (off * sizeof(float) > ws_size) return;  // insufficient workspace -> fail loudly

  const long sF = (long)NPTS*128;
  const long sC = (long)NPTS*512;

  // 1. prep: weights, pool init, xt, EC1 U/V
  k_prep<<<4976, 256, 0, stream>>>(x, W1, W2, W3, W4, W2m, W5,
                                   w2h, w2l, w3h, w3l, w4h, w4l, wmh, wml, w5h, w5l,
                                   p1, p2, xt, UVbuf);

  // 2. EC1: fused dist(C=3)+topk+gather -> x1 (+nrmA)
  k_topkg<true,64,true><<<BATCH*NPTS/4, 256, 0, stream>>>(
      xt, UVbuf, 128, g1, b1, fh, fl, 128, nrmA, nullptr);

  // 3. EC2: dist(K=64, tri) + UV(K=64) combined
  k_mgc<<<dim3(44,1,BATCH), 256, 0, stream>>>(fh, fl, 128, sF, w2h, w2l,
                                              D, nrmA, UVbuf, 128, sF, 64, 36);
  // 4. EC2: topk+gather -> x2 (+nrmB chained)
  k_topkg<false,64,true><<<BATCH*NPTS/4, 256, 0, stream>>>(
      D, UVbuf, 128, g2, b2, fh + 64, fl + 64, 128, nrmB, nrmA);

  // 5. EC3: dist(K=128, tri) + UV(K=128) combined
  k_mgc<<<dim3(68,1,BATCH), 256, 0, stream>>>(fh, fl, 128, sF, w3h, w3l,
                                              D, nrmB, UVbuf, 512, sC, 128, 36);
  // 6. EC3: topk+gather -> x3 (+nrmC)
  k_topkg<false,256,true><<<BATCH*NPTS/4, 256, 0, stream>>>(
      D, UVbuf, 512, g3, b3, ch, cl, 512, nrmC, nullptr);

  // 7. EC4: dist(K=256, tri) + UV(K=256) combined
  k_mgc<<<dim3(68,1,BATCH), 256, 0, stream>>>(ch, cl, 512, sC, w4h, w4l,
                                              D, nrmC, UVbuf, 512, sC, 256, 36);
  // 8. EC4: topk+gather -> x4
  k_topkg<false,256,false><<<BATCH*NPTS/4, 256, 0, stream>>>(
      D, UVbuf, 512, g4, b4, ch + 256, cl + 256, 512, nullptr, nullptr);

  // 9. pools combined
  k_poolc<<<dim3(128,1,BATCH), 256, 0, stream>>>(
      fh, fl, wmh, wml, g2m, b2m, p1,
      ch, cl, w5h, w5l, g5, b5, p2);

  // 10-12. FC head
  k_fc1<<<128, 256, 0, stream>>>(p1, p2, L1, g6, b6, f1);
  k_fc2<<<64, 256, 0, stream>>>(f1, L2, bL2, g7, b7, f2);
  k_fc3<<<40, 64, 0, stream>>>(f2, L3, bL3, (float*)d_out);
}